// Round 7
// baseline (9880.316 us; speedup 1.0000x reference)
//
#include <hip/hip_runtime.h>
#include <hip/hip_bf16.h>
#include <cstdint>

// ============================================================================
// 2-layer LSTM prefix + 59-step decode, persistent kernel, round 12.
// Round-12 change (r11 confirmed order->error; residual ~12.5us/hop vs ~5us
// internal model; r10 null exonerated intra-hop load scheduling -> attack
// INTRA-BLOCK COUPLING):
//   * NO __syncthreads in the recurrence. Per-wave epilogue: consumer wave rg
//     reads exactly rows rg*32..rg*32+31 == the rows producer wave rg
//     computes, so the existing x4 flag replicas already partition the
//     dependency wave-to-wave. Each wave: gate math -> private 512B LDS
//     exchange (write, s_waitcnt lgkmcnt(0), read; wave-lockstep, no
//     barrier) -> 64x8B sc1 stores of its own row slice -> wave-local
//     vmcnt(0) drain -> lane0 flags replica rg. Consumer logic unchanged.
//   * Waves slip freely across the entire recurrence (reconverge only at the
//     L0 weight swap), turning block-level max-of-4-waves jitter into 1024
//     independent wave-chains.
//   * MFMA accumulation order per wave untouched (fresh-first ascending kk,
//     the absmax=2.44e-4 invariant from r11).
// Everything else (chunk-granular per-wave gating, full-line discovery,
// 4-chunk register window, LDS-resident weights, VGPR c-state, post-loop y)
// is r11 verbatim.
// ============================================================================

typedef _Float16 half_t;
typedef _Float16 half8 __attribute__((ext_vector_type(8)));
typedef float float4v __attribute__((ext_vector_type(4)));
typedef int int32x4_t __attribute__((ext_vector_type(4)));
typedef float float32x4_t __attribute__((ext_vector_type(4)));

__device__ float32x4_t llvm_amdgcn_raw_buffer_load_fp32x4(
    int32x4_t srsrc, int voffset, int soffset, int aux)
    __asm("llvm.amdgcn.raw.buffer.load.v4f32");

#define AUX_SC1 16  // device scope: bypass L1/L2, served by IF$

union SrdU { int32x4_t v; struct { const void* p; unsigned nr, fl; } s; };
__device__ __forceinline__ int32x4_t make_srd(const void* p) {
  SrdU u; u.s.p = p; u.s.nr = 0xFFFFFFFFu; u.s.fl = 0x00020000u; return u.v;
}

// Read 4 group counters device-coherently; bit i set iff p[i] >= 16.
__device__ __forceinline__ unsigned poll4(const int* p) {
  union { float32x4_t f; int i[4]; } u;
  u.f = llvm_amdgcn_raw_buffer_load_fp32x4(make_srd(p), 0, 0, AUX_SC1);
  unsigned m = 0;
  if (u.i[0] >= 16) m |= 1u;
  if (u.i[1] >= 16) m |= 2u;
  if (u.i[2] >= 16) m |= 4u;
  if (u.i[3] >= 16) m |= 8u;
  return m;
}

__device__ __forceinline__ unsigned peek8(const int* f) {
  return poll4(f) | (poll4(f + 4) << 4);
}

// Wave-level wait for group/chunk c; polls the FULL 8-group line each retry
// so any blocked wait also discovers all later groups. Trailing compiler
// barrier pins this chunk's A-load issue below the wait.
__device__ __forceinline__ void wait_chunk(const int* f, int c, unsigned& got) {
  if (!((got >> c) & 1)) {
    for (;;) {
      got |= peek8(f);
      if ((got >> c) & 1) break;
      __builtin_amdgcn_s_sleep(2);
    }
  }
  asm volatile("" ::: "memory");
}

__device__ __forceinline__ void flag_add(int* p) {
  __hip_atomic_fetch_add(p, 1, __ATOMIC_RELAXED, __HIP_MEMORY_SCOPE_AGENT);
}

__device__ __forceinline__ float sigm_(float x) { return 1.0f / (1.0f + __expf(-x)); }
__device__ __forceinline__ float tanh_(float x) {
  float ax = fabsf(x);
  float e = __expf(-2.0f * ax);
  float t = (1.0f - e) / (1.0f + e);
  return x < 0.0f ? -t : t;
}

#define MFMA16(a, b, c) __builtin_amdgcn_mfma_f32_16x16x32_f16(a, b, c, 0, 0, 0)

// ---------------- pipelined chunk streaming ----------------
// A chunk = 128 K (4 kk-iters of MFMA 16x16x32) = 32 KB of fragment-linear A,
// produced exactly by flag-group c (blocks c*16..c*16+15).

__device__ __forceinline__ void issue_chunk(const half_t* __restrict__ A, int c,
                                            int ro, half8 (&a0)[4], half8 (&a1)[4]) {
#pragma unroll
  for (int k4 = 0; k4 < 4; ++k4) {
    const half_t* ap = A + (c * 16 + k4 * 4) * 1024 + ro;
    a0[k4] = *(const half8*)ap;
    a1[k4] = *(const half8*)(ap + 128);
  }
}

__device__ __forceinline__ void consume_chunk(const half8 (&a0)[4],
                                              const half8 (&a1)[4],
                                              const half_t* __restrict__ W, int kk0,
                                              int lq, int lrow, float4v acc[2][2]) {
#pragma unroll
  for (int k4 = 0; k4 < 4; ++k4) {
    const half_t* bp = W + (kk0 + k4) * 1024 + lq * 256 + lrow * 8;
    half8 b0 = *(const half8*)bp;
    half8 b1 = *(const half8*)(bp + 128);
    acc[0][0] = MFMA16(a0[k4], b0, acc[0][0]);
    acc[0][1] = MFMA16(a0[k4], b1, acc[0][1]);
    acc[1][0] = MFMA16(a1[k4], b0, acc[1][0]);
    acc[1][1] = MFMA16(a1[k4], b1, acc[1][1]);
  }
}

template <int NC>
__device__ __forceinline__ void issue_chunks(const half_t* __restrict__ A, int ro,
                                             half8 (&a0)[NC][4], half8 (&a1)[NC][4]) {
#pragma unroll
  for (int c = 0; c < NC; ++c) issue_chunk(A, c, ro, a0[c], a1[c]);
}

template <int NC>
__device__ __forceinline__ void consume_chunks(const half8 (&a0)[NC][4],
                                               const half8 (&a1)[NC][4],
                                               const half_t* __restrict__ W, int kk0,
                                               int lq, int lrow, float4v acc[2][2]) {
#pragma unroll
  for (int c = 0; c < NC; ++c)
    consume_chunk(a0[c], a1[c], W, kk0 + c * 4, lq, lrow, acc);
}

// 8-chunk (K=1024) gated stream: 4-chunk register window, per-wave waits,
// no intra-block barriers.
__device__ __forceinline__ void stream8g(const half_t* __restrict__ A,
                                         const half_t* __restrict__ W, int kk0,
                                         const int* f, unsigned got,
                                         int ro, int lq, int lrow, float4v acc[2][2]) {
  half8 a0[4][4], a1[4][4];
#pragma unroll
  for (int c = 0; c < 4; ++c) {
    wait_chunk(f, c, got);
    issue_chunk(A, c, ro, a0[c], a1[c]);
  }
#pragma unroll
  for (int c = 0; c < 8; ++c) {
    consume_chunk(a0[c & 3], a1[c & 3], W, kk0 + c * 4, lq, lrow, acc);
    if (c < 4) {
      wait_chunk(f, c + 4, got);
      issue_chunk(A, c + 4, ro, a0[c & 3], a1[c & 3]);
    }
  }
}

// L0-prefix stream: ungated XH (2 chunks, kk 0..7) issued first and consumed
// while the gated H prologue loads are in flight; H covers kk 8..39.
__device__ __forceinline__ void stream_l0p(const half_t* __restrict__ XHs,
                                           const half_t* __restrict__ A,
                                           const half_t* __restrict__ W,
                                           const int* f, int ro, int lq, int lrow,
                                           float4v acc[2][2]) {
  half8 xa0[2][4], xa1[2][4];
  issue_chunks<2>(XHs, ro, xa0, xa1);
  unsigned got = peek8(f);
  half8 a0[4][4], a1[4][4];
#pragma unroll
  for (int c = 0; c < 4; ++c) {
    wait_chunk(f, c, got);
    issue_chunk(A, c, ro, a0[c], a1[c]);
  }
  consume_chunk(xa0[0], xa1[0], W, 0, lq, lrow, acc);
  consume_chunk(xa0[1], xa1[1], W, 4, lq, lrow, acc);
#pragma unroll
  for (int c = 0; c < 8; ++c) {
    consume_chunk(a0[c & 3], a1[c & 3], W, 8 + c * 4, lq, lrow, acc);
    if (c < 4) {
      wait_chunk(f, c + 4, got);
      issue_chunk(A, c + 4, ro, a0[c & 3], a1[c & 3]);
    }
  }
}

// Per-wave cell epilogue for this wave's 32 rows of the [128 x 32] gate tile.
// c persists in 4 VGPRs. h exchanged through the wave's PRIVATE 512B LDS
// region (no barrier: wave-lockstep + lgkmcnt(0)), stored sc1 (64 x 8B),
// drained wave-locally (vmcnt(0)). Caller flags replica rg afterwards.
__device__ __forceinline__ void epi_gates(
    float4v acc[2][2], int tile, const float* __restrict__ biasArr,
    float c[2][2], half_t* hTileW, half_t* __restrict__ hDstW, int l) {
  const int lrow = l & 15, lq = l >> 4, q = l & 3, a = lrow >> 2;
#pragma unroll
  for (int m = 0; m < 2; ++m)
#pragma unroll
    for (int nf = 0; nf < 2; ++nf) {
      const float bias = biasArr[tile * 32 + nf * 16 + lrow];
      float gi = 0.f, gf = 0.f, gg = 0.f, go = 0.f;
#pragma unroll
      for (int r = 0; r < 4; ++r) {
        float x = acc[m][nf][r] + bias;
        float t1 = __shfl_xor(x, 1);
        float t2 = __shfl_xor(x, 2);
        float t3 = __shfl_xor(x, 3);
        if (r == q) {
          gi = (q == 0) ? x : (q == 1 ? t1 : (q == 2 ? t2 : t3));
          gf = (q == 1) ? x : (q == 0 ? t1 : (q == 3 ? t2 : t3));
          gg = (q == 2) ? x : (q == 3 ? t1 : (q == 0 ? t2 : t3));
          go = (q == 3) ? x : (q == 2 ? t1 : (q == 1 ? t2 : t3));
        }
      }
      const int lr = m * 16 + lq * 4 + q;  // local row within this wave's 32
      const int ju = nf * 4 + a;
      float iv = sigm_(gi), fv = sigm_(gf), gv = tanh_(gg), ov = sigm_(go);
      float cnew = fv * c[m][nf] + iv * gv;
      c[m][nf] = cnew;
      hTileW[lr * 8 + ju] = (half_t)(ov * tanh_(cnew));
    }
  // wave-private LDS exchange: writes above, reads below, same wave only
  asm volatile("s_waitcnt lgkmcnt(0)" ::: "memory");
  {
    const int r = l >> 1, hh = l & 1;  // 32 rows x 2 halves, 8B per lane
    unsigned long long v = *(const unsigned long long*)(hTileW + r * 8 + hh * 4);
    unsigned long long* d = (unsigned long long*)(hDstW + r * 8 + hh * 4);
    __hip_atomic_store(d, v, __ATOMIC_RELAXED, __HIP_MEMORY_SCOPE_AGENT);
  }
  asm volatile("s_waitcnt vmcnt(0)" ::: "memory");  // wave-local drain
}

__device__ __forceinline__ void epi_y(
    float4v acc[2][2], int ytile, int i, const float* __restrict__ biasY,
    float* __restrict__ out, int tid) {
  const int l = tid & 63, rg = tid >> 6;
  const int lrow = l & 15, lq = l >> 4;
#pragma unroll
  for (int m = 0; m < 2; ++m)
#pragma unroll
    for (int nf = 0; nf < 2; ++nf) {
      const int d = ytile * 32 + nf * 16 + lrow;
      const float b = biasY[d];
#pragma unroll
      for (int r = 0; r < 4; ++r) {
        const int row = rg * 32 + m * 16 + lq * 4 + r;
        out[(long)row * 15360 + i * 256 + d] = acc[m][nf][r] + b;
      }
    }
}

__device__ __forceinline__ void loadW(const half_t* __restrict__ src,
                                      half_t* dst, int halves, int tid) {
  for (int i = tid * 8; i < halves; i += 2048)
    *(uint4*)(dst + i) = *(const uint4*)(src + i);
}

#define ZACC2 float4v acc[2][2]; { float4v z = {0.f, 0.f, 0.f, 0.f}; \
  acc[0][0] = z; acc[0][1] = z; acc[1][0] = z; acc[1][1] = z; }

__global__ void __launch_bounds__(256, 1) k_lstm(
    const half_t* __restrict__ S0, const half_t* __restrict__ S1,
    const half_t* __restrict__ SD, const half_t* __restrict__ SY,
    const half_t* __restrict__ XH,
    half_t* __restrict__ H0, half_t* __restrict__ H1,
    const float* __restrict__ B0P, const float* __restrict__ B1P,
    const float* __restrict__ BD0P, float* __restrict__ out, int* FLGB) {
  __shared__ char smem[133120];  // 128 KB W (persistent) + 4 x 512B wave hTile
  half_t* ldsW = (half_t*)smem;
  const int w = blockIdx.x, tid = threadIdx.x;
  const int l = tid & 63, rg = tid >> 6;
  const int lrow = l & 15, lq = l >> 4;
  const int ro = (rg * 32 + lrow) * 8 + lq * 1024;
  half_t* hTileW = (half_t*)(smem + 131072) + rg * 256;  // this wave's 512B
  const int hOffW = rg * 256;  // this wave's 32-row slice within a 2KB region
  float c2[2][2] = {{0.f, 0.f}, {0.f, 0.f}};
#define SLOTP(base, idx) ((base) + (long)(idx) * 131072)
// flag record for (step, layer) replica rg: 32 ints (128 B), counters to 16
#define FREC(s, lay, rr) (FLGB + ((((s) * 2 + (lay)) * 4 + (rr)) << 5))

  if (w < 128) {  // ============ L0 prefix + decode cell0 ============
    const int g = w >> 4;
    loadW(S0 + (long)w * 40960, ldsW, 40960, tid);
    __syncthreads();
    {  // s = 0: H0[0] == 0 -> XH contribution only
      ZACC2;
      half8 xa0[2][4], xa1[2][4];
      issue_chunks<2>(XH, ro, xa0, xa1);
      consume_chunks<2>(xa0, xa1, ldsW, 0, lq, lrow, acc);
      epi_gates(acc, w, B0P, c2, hTileW, SLOTP(H0, 1) + w * 1024 + hOffW, l);
      if (l == 0) flag_add(FREC(0, 0, rg) + g);
    }
    for (int s = 1; s < 256; ++s) {
      ZACC2;
      stream_l0p(XH + (long)s * 32768, SLOTP(H0, s), ldsW, FREC(s - 1, 0, rg),
                 ro, lq, lrow, acc);
      epi_gates(acc, w, B0P, c2, hTileW, SLOTP(H0, s + 1) + w * 1024 + hOffW, l);
      if (l == 0) flag_add(FREC(s, 0, rg) + g);
    }
    __syncthreads();  // reconverge before overwriting LDS weights
    loadW(SD + (long)w * 65536, ldsW, 65536, tid);  // swap in Weff|Whh0
    __syncthreads();
    for (int i = 0; i < 59; ++i) {
      ZACC2;
      const int* fF = FREC(256 + i, 1, rg);  // fresh H1[256+i]
      const int* fO = FREC(255 + i, 0, rg);  // old own H0[256+i]
      unsigned gotO = peek8(fO);             // old discovery overlaps fresh
      // ascending kk (r7 order): fresh H1 -> Weff (kk 0..31) FIRST
      stream8g(SLOTP(H1, 256 + i), ldsW, 0, fF, 0u, ro, lq, lrow, acc);
      // then old H0 -> Whh0 (kk 32..63)
      stream8g(SLOTP(H0, 256 + i), ldsW, 32, fO, gotO, ro, lq, lrow, acc);
      epi_gates(acc, w, BD0P, c2, hTileW,
                SLOTP(H0, 257 + i) + w * 1024 + hOffW, l);
      if (l == 0) flag_add(FREC(256 + i, 0, rg) + g);
    }
  } else {  // ============ L1 prefix + decode cell1 ============
    const int bw = w - 128, g = bw >> 4;
    loadW(S1 + (long)bw * 65536, ldsW, 65536, tid);
    __syncthreads();
    for (int s = 1; s <= 256; ++s) {
      ZACC2;
      const int* fF = FREC(s - 1, 0, rg);  // fresh H0[s]
      const int* fO = FREC(s - 1, 1, rg);  // old H1[s-1]
      unsigned gotO = (s >= 2) ? peek8(fO) : 0u;
      // ascending kk: fresh H0[s] -> Wih1 (kk 0..31) FIRST
      stream8g(SLOTP(H0, s), ldsW, 0, fF, 0u, ro, lq, lrow, acc);
      // then old H1[s-1] -> Whh1 (kk 32..63); s == 1: H1[0] == 0 -> skip
      if (s >= 2)
        stream8g(SLOTP(H1, s - 1), ldsW, 32, fO, gotO, ro, lq, lrow, acc);
      epi_gates(acc, bw, B1P, c2, hTileW,
                SLOTP(H1, s) + bw * 1024 + hOffW, l);
      if (l == 0) flag_add(FREC(s, 1, rg) + g);
    }
    for (int i = 0; i < 59; ++i) {
      ZACC2;
      const int* fF = FREC(256 + i, 0, rg);  // fresh H0[257+i]
      const int* fO = FREC(256 + i, 1, rg);  // old own H1[256+i]
      unsigned gotO = peek8(fO);
      // ascending kk: fresh H0[257+i] -> Wih1 (kk 0..31) FIRST
      stream8g(SLOTP(H0, 257 + i), ldsW, 0, fF, 0u, ro, lq, lrow, acc);
      // then old H1[256+i] -> Whh1 (kk 32..63)
      stream8g(SLOTP(H1, 256 + i), ldsW, 32, fO, gotO, ro, lq, lrow, acc);
      epi_gates(acc, bw, B1P, c2, hTileW,
                SLOTP(H1, 257 + i) + bw * 1024 + hOffW, l);
      if (l == 0) flag_add(FREC(257 + i, 1, rg) + g);
    }
  }

  // ---- post-loop: y[i] = H1[256+i] @ Wlin^T + b, i = 0..59, 8 col-tiles ----
  // 480 tile-jobs over 256 blocks; off the recurrence chain entirely.
  for (int j = w; j < 480; j += 256) {
    const int i = j >> 3, t = j & 7;
    ZACC2;
    const int* f = FREC(256 + i, 1, rg);
    stream8g(SLOTP(H1, 256 + i), SY + (long)t * 32768, 0, f, peek8(f),
             ro, lq, lrow, acc);
    epi_y(acc, t, i, BD0P + 4096, out, tid);
  }
#undef FREC
#undef SLOTP
}

// ======================= setup kernels (round-5 verbatim) ===================

__global__ void k_cvt_x(const float* __restrict__ x, half_t* __restrict__ XH) {
  int idx = blockIdx.x * 256 + threadIdx.x;  // 1,048,576 total
  int t = idx >> 12;
  int kb = (idx >> 7) & 31;
  int r = idx & 127;
  const float* src = x + ((long)((r << 8) + t)) * 256 + kb * 8;
  float4 v0 = *(const float4*)src;
  float4 v1 = *(const float4*)(src + 4);
  half_t tmp[8] = {(half_t)v0.x, (half_t)v0.y, (half_t)v0.z, (half_t)v0.w,
                   (half_t)v1.x, (half_t)v1.y, (half_t)v1.z, (half_t)v1.w};
  *(uint4*)(XH + (long)t * 32768 + kb * 1024 + r * 8) = *(const uint4*)tmp;
}

__global__ void k_pack32(const float* __restrict__ A, int KA,
                         const float* __restrict__ Bsrc,
                         half_t* __restrict__ dst, int KT32, int skipA) {
  int idx = blockIdx.x * 256 + threadIdx.x;
  int nn = idx & 31;
  int lq = (idx >> 5) & 3;
  int t2 = idx >> 7;
  int kk = t2 % KT32;
  int tile = t2 / KT32;
  if (tile >= 128) return;
  int k = kk * 32 + lq * 8;
  int rp = tile * 32 + nn;
  int r = ((rp & 3) << 10) + (rp >> 2);
  const float* src;
  if (k < KA) {
    if (skipA) return;
    src = A + (long)r * KA + k;
  } else {
    src = Bsrc + (long)r * 1024 + (k - KA);
  }
  float4 v0 = *(const float4*)src;
  float4 v1 = *(const float4*)(src + 4);
  half_t tmp[8] = {(half_t)v0.x, (half_t)v0.y, (half_t)v0.z, (half_t)v0.w,
                   (half_t)v1.x, (half_t)v1.y, (half_t)v1.z, (half_t)v1.w};
  *(uint4*)(dst + (long)tile * (KT32 * 1024) + kk * 1024 + lq * 256 + nn * 8) =
      *(const uint4*)tmp;
}

__global__ void k_pack_y32(const float* __restrict__ Wlin,
                           half_t* __restrict__ SY) {
  int idx = blockIdx.x * 256 + threadIdx.x;  // 32768 total
  int nn = idx & 31;
  int lq = (idx >> 5) & 3;
  int kk = (idx >> 7) & 31;
  int tile = idx >> 12;
  int d = tile * 32 + nn;
  int k = kk * 32 + lq * 8;
  const float* src = Wlin + (long)d * 1024 + k;
  float4 v0 = *(const float4*)src;
  float4 v1 = *(const float4*)(src + 4);
  half_t tmp[8] = {(half_t)v0.x, (half_t)v0.y, (half_t)v0.z, (half_t)v0.w,
                   (half_t)v1.x, (half_t)v1.y, (half_t)v1.z, (half_t)v1.w};
  *(uint4*)(SY + (long)tile * 32768 + kk * 1024 + lq * 256 + nn * 8) =
      *(const uint4*)tmp;
}

__global__ void k_bias_simple(const float* bi0, const float* bh0,
                              const float* bi1, const float* bh1,
                              const float* blin, float* b0p, float* b1p,
                              float* bD0p) {
  int rp = blockIdx.x * blockDim.x + threadIdx.x;
  if (rp < 4096) {
    int r = ((rp & 3) << 10) + (rp >> 2);
    b0p[rp] = bi0[r] + bh0[r];
    b1p[rp] = bi1[r] + bh1[r];
  } else if (rp < 4352) {
    bD0p[rp] = blin[rp - 4096];
  }
}

__global__ void k_bias_dot(const float* __restrict__ Wih0,
                           const float* __restrict__ blin,
                           const float* __restrict__ bi0,
                           const float* __restrict__ bh0,
                           float* __restrict__ bD0p) {
  int wv = threadIdx.x >> 6, l = threadIdx.x & 63;
  int r = blockIdx.x * 4 + wv;
  float s = 0.f;
#pragma unroll
  for (int c = 0; c < 4; ++c) s += Wih0[r * 256 + c * 64 + l] * blin[c * 64 + l];
#pragma unroll
  for (int o = 32; o >= 1; o >>= 1) s += __shfl_xor(s, o);
  if (l == 0) {
    int rp = ((r & 1023) << 2) | (r >> 10);
    bD0p[rp] = bi0[r] + bh0[r] + s;
  }
}

__global__ void k_weff(const float* __restrict__ Wih0,
                       const float* __restrict__ Wlin,
                       half_t* __restrict__ SD) {
  __shared__ float At[64][65];
  __shared__ float Bt[64][65];
  const int rt = blockIdx.x, jt = blockIdx.y;
  const int tid = threadIdx.x;
  const int tx = tid & 15, ty = tid >> 4;
  float acc[4][4] = {};
  for (int k0 = 0; k0 < 256; k0 += 64) {
    __syncthreads();
#pragma unroll
    for (int i = 0; i < 16; ++i) {
      int lin = tid + 256 * i;
      int rr = lin >> 6, kk = lin & 63;
      At[rr][kk] = Wih0[(rt * 64 + rr) * 256 + k0 + kk];
      Bt[rr][kk] = Wlin[(k0 + rr) * 1024 + jt * 64 + kk];
    }
    __syncthreads();
    for (int kk = 0; kk < 64; ++kk) {
      float a[4], b[4];
#pragma unroll
      for (int i = 0; i < 4; ++i) a[i] = At[ty * 4 + i][kk];
#pragma unroll
      for (int i = 0; i < 4; ++i) b[i] = Bt[kk][tx * 4 + i];
#pragma unroll
      for (int i = 0; i < 4; ++i)
#pragma unroll
        for (int jx = 0; jx < 4; ++jx) acc[i][jx] += a[i] * b[jx];
    }
  }
#pragma unroll
  for (int i = 0; i < 4; ++i) {
    int r = rt * 64 + ty * 4 + i;
    int rp = ((r & 1023) << 2) | (r >> 10);
    int tile = rp >> 5, nn = rp & 31;
#pragma unroll
    for (int jx = 0; jx < 4; ++jx) {
      int j = jt * 64 + tx * 4 + jx;
      SD[(long)tile * 65536 + (j >> 5) * 1024 + ((j >> 3) & 3) * 256 + nn * 8 +
         (j & 7)] = (half_t)acc[i][jx];
    }
  }
}

// ======================= launch =======================

extern "C" void kernel_launch(void* const* d_in, const int* in_sizes, int n_in,
                              void* d_out, int out_size, void* d_ws, size_t ws_size,
                              hipStream_t stream) {
  (void)in_sizes; (void)n_in; (void)out_size; (void)ws_size;
  const float* x    = (const float*)d_in[0];
  const float* Wih0 = (const float*)d_in[1];
  const float* Whh0 = (const float*)d_in[2];
  const float* bi0  = (const float*)d_in[3];
  const float* bh0  = (const float*)d_in[4];
  const float* Wih1 = (const float*)d_in[5];
  const float* Whh1 = (const float*)d_in[6];
  const float* bi1  = (const float*)d_in[7];
  const float* bh1  = (const float*)d_in[8];
  const float* Wlin = (const float*)d_in[9];
  const float* blin = (const float*)d_in[10];
  float* out = (float*)d_out;
  char* ws = (char*)d_ws;

  half_t* S0  = (half_t*)(ws + 0);         // 128 x 40960 x 2 = 10 MB
  half_t* S1  = (half_t*)(ws + 10485760);  // 128 x 65536 x 2 = 16 MB
  half_t* SD  = (half_t*)(ws + 27262976);  // 16 MB
  half_t* SY  = (half_t*)(ws + 44040192);  // 512 KB
  half_t* XH  = (half_t*)(ws + 44564480);  // 16 MB
  float*  B0P = (float*)(ws + 61341696);   // 16 KB
  float*  B1P = (float*)(ws + 61358080);   // 16 KB
  float*  BD0P= (float*)(ws + 61374464);   // 17408 B
  half_t* H0  = (half_t*)(ws + 61432320);  // ring: 320 x 256 KB = 80 MB
  half_t* H1  = (half_t*)(ws + 145318400); // ring: 320 x 256 KB = 80 MB
  // flag counters (x4 wave replicas) in the spare tail slots of the H1 ring
  // (slots 316..319 never written by the recurrence): 2560 lines x 128 B
  int*    FLGB= (int*)(ws + 145318400 + (long)316 * 262144);  // 228,155,904

  hipMemsetAsync(FLGB, 0, 327680, stream);     // all flag records
  hipMemsetAsync(H0, 0, 262144, stream);       // H0 slot 0 (safety; unused)
  hipMemsetAsync(H1, 0, 262144, stream);       // H1 slot 0 (safety; unused)

  k_cvt_x<<<4096, 256, 0, stream>>>(x, XH);
  k_bias_simple<<<17, 256, 0, stream>>>(bi0, bh0, bi1, bh1, blin, B0P, B1P, BD0P);
  k_bias_dot<<<1024, 256, 0, stream>>>(Wih0, blin, bi0, bh0, BD0P);
  k_pack32<<<2560, 256, 0, stream>>>(Wih0, 256, Whh0, S0, 40, 0);
  k_pack32<<<4096, 256, 0, stream>>>(Wih1, 1024, Whh1, S1, 64, 0);
  k_pack32<<<4096, 256, 0, stream>>>(nullptr, 1024, Whh0, SD, 64, 1);
  k_pack_y32<<<128, 256, 0, stream>>>(Wlin, SY);
  k_weff<<<dim3(64, 16), 256, 0, stream>>>(Wih0, Wlin, SD);

  k_lstm<<<256, 256, 0, stream>>>(S0, S1, SD, SY, XH, H0, H1,
                                  B0P, B1P, BD0P, out, FLGB);
}

// Round 8
// 5949.551 us; speedup vs baseline: 1.6607x; 1.6607x over previous
//
#include <hip/hip_runtime.h>
#include <hip/hip_bf16.h>
#include <cstdint>

// ============================================================================
// 2-layer LSTM prefix + 59-step decode, persistent kernel, round 13.
// Round-13 (r12 post-mortem: full decoupling -> spin pathology, 2x slower
// with 9.8-36ms variance; but per-wave flag/store protocol proven correct.
// r11 vs r12 isolates: the win is the FLAG OFF THE BARRIER PATH, not barrier
// removal):
//   * r11 base + per-wave epilogue with EARLY FLAG: each wave exchanges h
//     through its private 512B LDS region (write -> lgkmcnt(0)+sched_barrier
//     -> read), stores ITS OWN 32 rows (64x8B sc1), drains wave-locally
//     (vmcnt(0)), lane0 raises replica rg immediately -- block-mates are not
//     on the producer->consumer chain.
//   * ONE __syncthreads per hop AFTER the flag: bounds intra-block slip to
//     <=1 hop (kills the r12 spin pathology) while keeping reconvergence off
//     the critical handoff.
//   * Streams, chunk gating, fresh-first ascending-kk accumulation order:
//     r11 verbatim (absmax=2.441e-4 invariant).
// ============================================================================

typedef _Float16 half_t;
typedef _Float16 half8 __attribute__((ext_vector_type(8)));
typedef float float4v __attribute__((ext_vector_type(4)));
typedef int int32x4_t __attribute__((ext_vector_type(4)));
typedef float float32x4_t __attribute__((ext_vector_type(4)));

__device__ float32x4_t llvm_amdgcn_raw_buffer_load_fp32x4(
    int32x4_t srsrc, int voffset, int soffset, int aux)
    __asm("llvm.amdgcn.raw.buffer.load.v4f32");

#define AUX_SC1 16  // device scope: bypass L1/L2, served by IF$

union SrdU { int32x4_t v; struct { const void* p; unsigned nr, fl; } s; };
__device__ __forceinline__ int32x4_t make_srd(const void* p) {
  SrdU u; u.s.p = p; u.s.nr = 0xFFFFFFFFu; u.s.fl = 0x00020000u; return u.v;
}

// Read 4 group counters device-coherently; bit i set iff p[i] >= 16.
__device__ __forceinline__ unsigned poll4(const int* p) {
  union { float32x4_t f; int i[4]; } u;
  u.f = llvm_amdgcn_raw_buffer_load_fp32x4(make_srd(p), 0, 0, AUX_SC1);
  unsigned m = 0;
  if (u.i[0] >= 16) m |= 1u;
  if (u.i[1] >= 16) m |= 2u;
  if (u.i[2] >= 16) m |= 4u;
  if (u.i[3] >= 16) m |= 8u;
  return m;
}

__device__ __forceinline__ unsigned peek8(const int* f) {
  return poll4(f) | (poll4(f + 4) << 4);
}

// Wave-level wait for group/chunk c; polls the FULL 8-group line each retry
// so any blocked wait also discovers all later groups. Trailing compiler
// barrier pins this chunk's A-load issue below the wait.
__device__ __forceinline__ void wait_chunk(const int* f, int c, unsigned& got) {
  if (!((got >> c) & 1)) {
    for (;;) {
      got |= peek8(f);
      if ((got >> c) & 1) break;
      __builtin_amdgcn_s_sleep(2);
    }
  }
  asm volatile("" ::: "memory");
}

__device__ __forceinline__ void flag_add(int* p) {
  __hip_atomic_fetch_add(p, 1, __ATOMIC_RELAXED, __HIP_MEMORY_SCOPE_AGENT);
}

__device__ __forceinline__ float sigm_(float x) { return 1.0f / (1.0f + __expf(-x)); }
__device__ __forceinline__ float tanh_(float x) {
  float ax = fabsf(x);
  float e = __expf(-2.0f * ax);
  float t = (1.0f - e) / (1.0f + e);
  return x < 0.0f ? -t : t;
}

#define MFMA16(a, b, c) __builtin_amdgcn_mfma_f32_16x16x32_f16(a, b, c, 0, 0, 0)

// ---------------- pipelined chunk streaming ----------------
// A chunk = 128 K (4 kk-iters of MFMA 16x16x32) = 32 KB of fragment-linear A,
// produced exactly by flag-group c (blocks c*16..c*16+15).

__device__ __forceinline__ void issue_chunk(const half_t* __restrict__ A, int c,
                                            int ro, half8 (&a0)[4], half8 (&a1)[4]) {
#pragma unroll
  for (int k4 = 0; k4 < 4; ++k4) {
    const half_t* ap = A + (c * 16 + k4 * 4) * 1024 + ro;
    a0[k4] = *(const half8*)ap;
    a1[k4] = *(const half8*)(ap + 128);
  }
}

__device__ __forceinline__ void consume_chunk(const half8 (&a0)[4],
                                              const half8 (&a1)[4],
                                              const half_t* __restrict__ W, int kk0,
                                              int lq, int lrow, float4v acc[2][2]) {
#pragma unroll
  for (int k4 = 0; k4 < 4; ++k4) {
    const half_t* bp = W + (kk0 + k4) * 1024 + lq * 256 + lrow * 8;
    half8 b0 = *(const half8*)bp;
    half8 b1 = *(const half8*)(bp + 128);
    acc[0][0] = MFMA16(a0[k4], b0, acc[0][0]);
    acc[0][1] = MFMA16(a0[k4], b1, acc[0][1]);
    acc[1][0] = MFMA16(a1[k4], b0, acc[1][0]);
    acc[1][1] = MFMA16(a1[k4], b1, acc[1][1]);
  }
}

template <int NC>
__device__ __forceinline__ void issue_chunks(const half_t* __restrict__ A, int ro,
                                             half8 (&a0)[NC][4], half8 (&a1)[NC][4]) {
#pragma unroll
  for (int c = 0; c < NC; ++c) issue_chunk(A, c, ro, a0[c], a1[c]);
}

template <int NC>
__device__ __forceinline__ void consume_chunks(const half8 (&a0)[NC][4],
                                               const half8 (&a1)[NC][4],
                                               const half_t* __restrict__ W, int kk0,
                                               int lq, int lrow, float4v acc[2][2]) {
#pragma unroll
  for (int c = 0; c < NC; ++c)
    consume_chunk(a0[c], a1[c], W, kk0 + c * 4, lq, lrow, acc);
}

// 8-chunk (K=1024) gated stream: 4-chunk register window, per-wave waits,
// no intra-block barriers.
__device__ __forceinline__ void stream8g(const half_t* __restrict__ A,
                                         const half_t* __restrict__ W, int kk0,
                                         const int* f, unsigned got,
                                         int ro, int lq, int lrow, float4v acc[2][2]) {
  half8 a0[4][4], a1[4][4];
#pragma unroll
  for (int c = 0; c < 4; ++c) {
    wait_chunk(f, c, got);
    issue_chunk(A, c, ro, a0[c], a1[c]);
  }
#pragma unroll
  for (int c = 0; c < 8; ++c) {
    consume_chunk(a0[c & 3], a1[c & 3], W, kk0 + c * 4, lq, lrow, acc);
    if (c < 4) {
      wait_chunk(f, c + 4, got);
      issue_chunk(A, c + 4, ro, a0[c & 3], a1[c & 3]);
    }
  }
}

// L0-prefix stream: ungated XH (2 chunks, kk 0..7) issued first and consumed
// while the gated H prologue loads are in flight; H covers kk 8..39.
__device__ __forceinline__ void stream_l0p(const half_t* __restrict__ XHs,
                                           const half_t* __restrict__ A,
                                           const half_t* __restrict__ W,
                                           const int* f, int ro, int lq, int lrow,
                                           float4v acc[2][2]) {
  half8 xa0[2][4], xa1[2][4];
  issue_chunks<2>(XHs, ro, xa0, xa1);
  unsigned got = peek8(f);
  half8 a0[4][4], a1[4][4];
#pragma unroll
  for (int c = 0; c < 4; ++c) {
    wait_chunk(f, c, got);
    issue_chunk(A, c, ro, a0[c], a1[c]);
  }
  consume_chunk(xa0[0], xa1[0], W, 0, lq, lrow, acc);
  consume_chunk(xa0[1], xa1[1], W, 4, lq, lrow, acc);
#pragma unroll
  for (int c = 0; c < 8; ++c) {
    consume_chunk(a0[c & 3], a1[c & 3], W, 8 + c * 4, lq, lrow, acc);
    if (c < 4) {
      wait_chunk(f, c + 4, got);
      issue_chunk(A, c + 4, ro, a0[c & 3], a1[c & 3]);
    }
  }
}

// Per-wave cell epilogue (r12-verified protocol): gate math -> private 512B
// LDS exchange (wave-lockstep, lgkmcnt(0)+sched_barrier, no block barrier) ->
// 64x8B sc1 stores of this wave's 32 rows -> wave-local vmcnt(0) drain.
// Caller raises replica rg immediately after, then a single __syncthreads
// bounds intra-block slip to <=1 hop.
__device__ __forceinline__ void epi_gates(
    float4v acc[2][2], int tile, const float* __restrict__ biasArr,
    float c[2][2], half_t* hTileW, half_t* __restrict__ hDstW, int l) {
  const int lrow = l & 15, lq = l >> 4, q = l & 3, a = lrow >> 2;
#pragma unroll
  for (int m = 0; m < 2; ++m)
#pragma unroll
    for (int nf = 0; nf < 2; ++nf) {
      const float bias = biasArr[tile * 32 + nf * 16 + lrow];
      float gi = 0.f, gf = 0.f, gg = 0.f, go = 0.f;
#pragma unroll
      for (int r = 0; r < 4; ++r) {
        float x = acc[m][nf][r] + bias;
        float t1 = __shfl_xor(x, 1);
        float t2 = __shfl_xor(x, 2);
        float t3 = __shfl_xor(x, 3);
        if (r == q) {
          gi = (q == 0) ? x : (q == 1 ? t1 : (q == 2 ? t2 : t3));
          gf = (q == 1) ? x : (q == 0 ? t1 : (q == 3 ? t2 : t3));
          gg = (q == 2) ? x : (q == 3 ? t1 : (q == 0 ? t2 : t3));
          go = (q == 3) ? x : (q == 2 ? t1 : (q == 1 ? t2 : t3));
        }
      }
      const int lr = m * 16 + lq * 4 + q;  // local row within this wave's 32
      const int ju = nf * 4 + a;
      float iv = sigm_(gi), fv = sigm_(gf), gv = tanh_(gg), ov = sigm_(go);
      float cnew = fv * c[m][nf] + iv * gv;
      c[m][nf] = cnew;
      hTileW[lr * 8 + ju] = (half_t)(ov * tanh_(cnew));
    }
  // wave-private LDS exchange: writes above, reads below, same wave only
  asm volatile("s_waitcnt lgkmcnt(0)" ::: "memory");
  __builtin_amdgcn_sched_barrier(0);
  {
    const int r = l >> 1, hh = l & 1;  // 32 rows x 2 halves, 8B per lane
    unsigned long long v = *(const unsigned long long*)(hTileW + r * 8 + hh * 4);
    unsigned long long* d = (unsigned long long*)(hDstW + r * 8 + hh * 4);
    __hip_atomic_store(d, v, __ATOMIC_RELAXED, __HIP_MEMORY_SCOPE_AGENT);
  }
  asm volatile("s_waitcnt vmcnt(0)" ::: "memory");  // wave-local drain
}

__device__ __forceinline__ void epi_y(
    float4v acc[2][2], int ytile, int i, const float* __restrict__ biasY,
    float* __restrict__ out, int tid) {
  const int l = tid & 63, rg = tid >> 6;
  const int lrow = l & 15, lq = l >> 4;
#pragma unroll
  for (int m = 0; m < 2; ++m)
#pragma unroll
    for (int nf = 0; nf < 2; ++nf) {
      const int d = ytile * 32 + nf * 16 + lrow;
      const float b = biasY[d];
#pragma unroll
      for (int r = 0; r < 4; ++r) {
        const int row = rg * 32 + m * 16 + lq * 4 + r;
        out[(long)row * 15360 + i * 256 + d] = acc[m][nf][r] + b;
      }
    }
}

__device__ __forceinline__ void loadW(const half_t* __restrict__ src,
                                      half_t* dst, int halves, int tid) {
  for (int i = tid * 8; i < halves; i += 2048)
    *(uint4*)(dst + i) = *(const uint4*)(src + i);
}

#define ZACC2 float4v acc[2][2]; { float4v z = {0.f, 0.f, 0.f, 0.f}; \
  acc[0][0] = z; acc[0][1] = z; acc[1][0] = z; acc[1][1] = z; }

__global__ void __launch_bounds__(256, 1) k_lstm(
    const half_t* __restrict__ S0, const half_t* __restrict__ S1,
    const half_t* __restrict__ SD, const half_t* __restrict__ SY,
    const half_t* __restrict__ XH,
    half_t* __restrict__ H0, half_t* __restrict__ H1,
    const float* __restrict__ B0P, const float* __restrict__ B1P,
    const float* __restrict__ BD0P, float* __restrict__ out, int* FLGB) {
  __shared__ char smem[133120];  // 128 KB W (persistent) + 4 x 512B wave hTile
  half_t* ldsW = (half_t*)smem;
  const int w = blockIdx.x, tid = threadIdx.x;
  const int l = tid & 63, rg = tid >> 6;
  const int lrow = l & 15, lq = l >> 4;
  const int ro = (rg * 32 + lrow) * 8 + lq * 1024;
  half_t* hTileW = (half_t*)(smem + 131072) + rg * 256;  // this wave's 512B
  const int hOffW = rg * 256;  // this wave's 32-row slice within a 2KB region
  float c2[2][2] = {{0.f, 0.f}, {0.f, 0.f}};
#define SLOTP(base, idx) ((base) + (long)(idx) * 131072)
// flag record for (step, layer) replica rg: 32 ints (128 B), counters to 16
#define FREC(s, lay, rr) (FLGB + ((((s) * 2 + (lay)) * 4 + (rr)) << 5))

  if (w < 128) {  // ============ L0 prefix + decode cell0 ============
    const int g = w >> 4;
    loadW(S0 + (long)w * 40960, ldsW, 40960, tid);
    __syncthreads();
    {  // s = 0: H0[0] == 0 -> XH contribution only
      ZACC2;
      half8 xa0[2][4], xa1[2][4];
      issue_chunks<2>(XH, ro, xa0, xa1);
      consume_chunks<2>(xa0, xa1, ldsW, 0, lq, lrow, acc);
      epi_gates(acc, w, B0P, c2, hTileW, SLOTP(H0, 1) + w * 1024 + hOffW, l);
      if (l == 0) flag_add(FREC(0, 0, rg) + g);
      __syncthreads();  // bound slip; off the producer->consumer chain
    }
    for (int s = 1; s < 256; ++s) {
      ZACC2;
      stream_l0p(XH + (long)s * 32768, SLOTP(H0, s), ldsW, FREC(s - 1, 0, rg),
                 ro, lq, lrow, acc);
      epi_gates(acc, w, B0P, c2, hTileW, SLOTP(H0, s + 1) + w * 1024 + hOffW, l);
      if (l == 0) flag_add(FREC(s, 0, rg) + g);
      __syncthreads();
    }
    __syncthreads();  // reconverge before overwriting LDS weights
    loadW(SD + (long)w * 65536, ldsW, 65536, tid);  // swap in Weff|Whh0
    __syncthreads();
    for (int i = 0; i < 59; ++i) {
      ZACC2;
      const int* fF = FREC(256 + i, 1, rg);  // fresh H1[256+i]
      const int* fO = FREC(255 + i, 0, rg);  // old own H0[256+i]
      unsigned gotO = peek8(fO);             // old discovery overlaps fresh
      // ascending kk (r7 order): fresh H1 -> Weff (kk 0..31) FIRST
      stream8g(SLOTP(H1, 256 + i), ldsW, 0, fF, 0u, ro, lq, lrow, acc);
      // then old H0 -> Whh0 (kk 32..63)
      stream8g(SLOTP(H0, 256 + i), ldsW, 32, fO, gotO, ro, lq, lrow, acc);
      epi_gates(acc, w, BD0P, c2, hTileW,
                SLOTP(H0, 257 + i) + w * 1024 + hOffW, l);
      if (l == 0) flag_add(FREC(256 + i, 0, rg) + g);
      __syncthreads();
    }
  } else {  // ============ L1 prefix + decode cell1 ============
    const int bw = w - 128, g = bw >> 4;
    loadW(S1 + (long)bw * 65536, ldsW, 65536, tid);
    __syncthreads();
    for (int s = 1; s <= 256; ++s) {
      ZACC2;
      const int* fF = FREC(s - 1, 0, rg);  // fresh H0[s]
      const int* fO = FREC(s - 1, 1, rg);  // old H1[s-1]
      unsigned gotO = (s >= 2) ? peek8(fO) : 0u;
      // ascending kk: fresh H0[s] -> Wih1 (kk 0..31) FIRST
      stream8g(SLOTP(H0, s), ldsW, 0, fF, 0u, ro, lq, lrow, acc);
      // then old H1[s-1] -> Whh1 (kk 32..63); s == 1: H1[0] == 0 -> skip
      if (s >= 2)
        stream8g(SLOTP(H1, s - 1), ldsW, 32, fO, gotO, ro, lq, lrow, acc);
      epi_gates(acc, bw, B1P, c2, hTileW,
                SLOTP(H1, s) + bw * 1024 + hOffW, l);
      if (l == 0) flag_add(FREC(s, 1, rg) + g);
      __syncthreads();
    }
    for (int i = 0; i < 59; ++i) {
      ZACC2;
      const int* fF = FREC(256 + i, 0, rg);  // fresh H0[257+i]
      const int* fO = FREC(256 + i, 1, rg);  // old own H1[256+i]
      unsigned gotO = peek8(fO);
      // ascending kk: fresh H0[257+i] -> Wih1 (kk 0..31) FIRST
      stream8g(SLOTP(H0, 257 + i), ldsW, 0, fF, 0u, ro, lq, lrow, acc);
      // then old H1[256+i] -> Whh1 (kk 32..63)
      stream8g(SLOTP(H1, 256 + i), ldsW, 32, fO, gotO, ro, lq, lrow, acc);
      epi_gates(acc, bw, B1P, c2, hTileW,
                SLOTP(H1, 257 + i) + bw * 1024 + hOffW, l);
      if (l == 0) flag_add(FREC(257 + i, 1, rg) + g);
      __syncthreads();
    }
  }

  // ---- post-loop: y[i] = H1[256+i] @ Wlin^T + b, i = 0..59, 8 col-tiles ----
  // 480 tile-jobs over 256 blocks; off the recurrence chain entirely.
  for (int j = w; j < 480; j += 256) {
    const int i = j >> 3, t = j & 7;
    ZACC2;
    const int* f = FREC(256 + i, 1, rg);
    stream8g(SLOTP(H1, 256 + i), SY + (long)t * 32768, 0, f, peek8(f),
             ro, lq, lrow, acc);
    epi_y(acc, t, i, BD0P + 4096, out, tid);
  }
#undef FREC
#undef SLOTP
}

// ======================= setup kernels (round-5 verbatim) ===================

__global__ void k_cvt_x(const float* __restrict__ x, half_t* __restrict__ XH) {
  int idx = blockIdx.x * 256 + threadIdx.x;  // 1,048,576 total
  int t = idx >> 12;
  int kb = (idx >> 7) & 31;
  int r = idx & 127;
  const float* src = x + ((long)((r << 8) + t)) * 256 + kb * 8;
  float4 v0 = *(const float4*)src;
  float4 v1 = *(const float4*)(src + 4);
  half_t tmp[8] = {(half_t)v0.x, (half_t)v0.y, (half_t)v0.z, (half_t)v0.w,
                   (half_t)v1.x, (half_t)v1.y, (half_t)v1.z, (half_t)v1.w};
  *(uint4*)(XH + (long)t * 32768 + kb * 1024 + r * 8) = *(const uint4*)tmp;
}

__global__ void k_pack32(const float* __restrict__ A, int KA,
                         const float* __restrict__ Bsrc,
                         half_t* __restrict__ dst, int KT32, int skipA) {
  int idx = blockIdx.x * 256 + threadIdx.x;
  int nn = idx & 31;
  int lq = (idx >> 5) & 3;
  int t2 = idx >> 7;
  int kk = t2 % KT32;
  int tile = t2 / KT32;
  if (tile >= 128) return;
  int k = kk * 32 + lq * 8;
  int rp = tile * 32 + nn;
  int r = ((rp & 3) << 10) + (rp >> 2);
  const float* src;
  if (k < KA) {
    if (skipA) return;
    src = A + (long)r * KA + k;
  } else {
    src = Bsrc + (long)r * 1024 + (k - KA);
  }
  float4 v0 = *(const float4*)src;
  float4 v1 = *(const float4*)(src + 4);
  half_t tmp[8] = {(half_t)v0.x, (half_t)v0.y, (half_t)v0.z, (half_t)v0.w,
                   (half_t)v1.x, (half_t)v1.y, (half_t)v1.z, (half_t)v1.w};
  *(uint4*)(dst + (long)tile * (KT32 * 1024) + kk * 1024 + lq * 256 + nn * 8) =
      *(const uint4*)tmp;
}

__global__ void k_pack_y32(const float* __restrict__ Wlin,
                           half_t* __restrict__ SY) {
  int idx = blockIdx.x * 256 + threadIdx.x;  // 32768 total
  int nn = idx & 31;
  int lq = (idx >> 5) & 3;
  int kk = (idx >> 7) & 31;
  int tile = idx >> 12;
  int d = tile * 32 + nn;
  int k = kk * 32 + lq * 8;
  const float* src = Wlin + (long)d * 1024 + k;
  float4 v0 = *(const float4*)src;
  float4 v1 = *(const float4*)(src + 4);
  half_t tmp[8] = {(half_t)v0.x, (half_t)v0.y, (half_t)v0.z, (half_t)v0.w,
                   (half_t)v1.x, (half_t)v1.y, (half_t)v1.z, (half_t)v1.w};
  *(uint4*)(SY + (long)tile * 32768 + kk * 1024 + lq * 256 + nn * 8) =
      *(const uint4*)tmp;
}

__global__ void k_bias_simple(const float* bi0, const float* bh0,
                              const float* bi1, const float* bh1,
                              const float* blin, float* b0p, float* b1p,
                              float* bD0p) {
  int rp = blockIdx.x * blockDim.x + threadIdx.x;
  if (rp < 4096) {
    int r = ((rp & 3) << 10) + (rp >> 2);
    b0p[rp] = bi0[r] + bh0[r];
    b1p[rp] = bi1[r] + bh1[r];
  } else if (rp < 4352) {
    bD0p[rp] = blin[rp - 4096];
  }
}

__global__ void k_bias_dot(const float* __restrict__ Wih0,
                           const float* __restrict__ blin,
                           const float* __restrict__ bi0,
                           const float* __restrict__ bh0,
                           float* __restrict__ bD0p) {
  int wv = threadIdx.x >> 6, l = threadIdx.x & 63;
  int r = blockIdx.x * 4 + wv;
  float s = 0.f;
#pragma unroll
  for (int c = 0; c < 4; ++c) s += Wih0[r * 256 + c * 64 + l] * blin[c * 64 + l];
#pragma unroll
  for (int o = 32; o >= 1; o >>= 1) s += __shfl_xor(s, o);
  if (l == 0) {
    int rp = ((r & 1023) << 2) | (r >> 10);
    bD0p[rp] = bi0[r] + bh0[r] + s;
  }
}

__global__ void k_weff(const float* __restrict__ Wih0,
                       const float* __restrict__ Wlin,
                       half_t* __restrict__ SD) {
  __shared__ float At[64][65];
  __shared__ float Bt[64][65];
  const int rt = blockIdx.x, jt = blockIdx.y;
  const int tid = threadIdx.x;
  const int tx = tid & 15, ty = tid >> 4;
  float acc[4][4] = {};
  for (int k0 = 0; k0 < 256; k0 += 64) {
    __syncthreads();
#pragma unroll
    for (int i = 0; i < 16; ++i) {
      int lin = tid + 256 * i;
      int rr = lin >> 6, kk = lin & 63;
      At[rr][kk] = Wih0[(rt * 64 + rr) * 256 + k0 + kk];
      Bt[rr][kk] = Wlin[(k0 + rr) * 1024 + jt * 64 + kk];
    }
    __syncthreads();
    for (int kk = 0; kk < 64; ++kk) {
      float a[4], b[4];
#pragma unroll
      for (int i = 0; i < 4; ++i) a[i] = At[ty * 4 + i][kk];
#pragma unroll
      for (int i = 0; i < 4; ++i) b[i] = Bt[kk][tx * 4 + i];
#pragma unroll
      for (int i = 0; i < 4; ++i)
#pragma unroll
        for (int jx = 0; jx < 4; ++jx) acc[i][jx] += a[i] * b[jx];
    }
  }
#pragma unroll
  for (int i = 0; i < 4; ++i) {
    int r = rt * 64 + ty * 4 + i;
    int rp = ((r & 1023) << 2) | (r >> 10);
    int tile = rp >> 5, nn = rp & 31;
#pragma unroll
    for (int jx = 0; jx < 4; ++jx) {
      int j = jt * 64 + tx * 4 + jx;
      SD[(long)tile * 65536 + (j >> 5) * 1024 + ((j >> 3) & 3) * 256 + nn * 8 +
         (j & 7)] = (half_t)acc[i][jx];
    }
  }
}

// ======================= launch =======================

extern "C" void kernel_launch(void* const* d_in, const int* in_sizes, int n_in,
                              void* d_out, int out_size, void* d_ws, size_t ws_size,
                              hipStream_t stream) {
  (void)in_sizes; (void)n_in; (void)out_size; (void)ws_size;
  const float* x    = (const float*)d_in[0];
  const float* Wih0 = (const float*)d_in[1];
  const float* Whh0 = (const float*)d_in[2];
  const float* bi0  = (const float*)d_in[3];
  const float* bh0  = (const float*)d_in[4];
  const float* Wih1 = (const float*)d_in[5];
  const float* Whh1 = (const float*)d_in[6];
  const float* bi1  = (const float*)d_in[7];
  const float* bh1  = (const float*)d_in[8];
  const float* Wlin = (const float*)d_in[9];
  const float* blin = (const float*)d_in[10];
  float* out = (float*)d_out;
  char* ws = (char*)d_ws;

  half_t* S0  = (half_t*)(ws + 0);         // 128 x 40960 x 2 = 10 MB
  half_t* S1  = (half_t*)(ws + 10485760);  // 128 x 65536 x 2 = 16 MB
  half_t* SD  = (half_t*)(ws + 27262976);  // 16 MB
  half_t* SY  = (half_t*)(ws + 44040192);  // 512 KB
  half_t* XH  = (half_t*)(ws + 44564480);  // 16 MB
  float*  B0P = (float*)(ws + 61341696);   // 16 KB
  float*  B1P = (float*)(ws + 61358080);   // 16 KB
  float*  BD0P= (float*)(ws + 61374464);   // 17408 B
  half_t* H0  = (half_t*)(ws + 61432320);  // ring: 320 x 256 KB = 80 MB
  half_t* H1  = (half_t*)(ws + 145318400); // ring: 320 x 256 KB = 80 MB
  // flag counters (x4 wave replicas) in the spare tail slots of the H1 ring
  // (slots 316..319 never written by the recurrence): 2560 lines x 128 B
  int*    FLGB= (int*)(ws + 145318400 + (long)316 * 262144);  // 228,155,904

  hipMemsetAsync(FLGB, 0, 327680, stream);     // all flag records
  hipMemsetAsync(H0, 0, 262144, stream);       // H0 slot 0 (safety; unused)
  hipMemsetAsync(H1, 0, 262144, stream);       // H1 slot 0 (safety; unused)

  k_cvt_x<<<4096, 256, 0, stream>>>(x, XH);
  k_bias_simple<<<17, 256, 0, stream>>>(bi0, bh0, bi1, bh1, blin, B0P, B1P, BD0P);
  k_bias_dot<<<1024, 256, 0, stream>>>(Wih0, blin, bi0, bh0, BD0P);
  k_pack32<<<2560, 256, 0, stream>>>(Wih0, 256, Whh0, S0, 40, 0);
  k_pack32<<<4096, 256, 0, stream>>>(Wih1, 1024, Whh1, S1, 64, 0);
  k_pack32<<<4096, 256, 0, stream>>>(nullptr, 1024, Whh0, SD, 64, 1);
  k_pack_y32<<<128, 256, 0, stream>>>(Wlin, SY);
  k_weff<<<dim3(64, 16), 256, 0, stream>>>(Wih0, Wlin, SD);

  k_lstm<<<256, 256, 0, stream>>>(S0, S1, SD, SY, XH, H0, H1,
                                  B0P, B1P, BD0P, out, FLGB);
}

// Round 9
// 5620.911 us; speedup vs baseline: 1.7578x; 1.0585x over previous
//
#include <hip/hip_runtime.h>
#include <hip/hip_bf16.h>
#include <cstdint>

// ============================================================================
// 2-layer LSTM prefix + 59-step decode, persistent kernel, round 14.
// Round-14 (r13 post-mortem: BOTH decoupling variants regressed -> r11's
// block epilogue restored verbatim and frozen. New lever: the old-operand
// stream sits AFTER the fresh stream on the critical path only because of
// MFMA consumption order -- load order is free):
//   * OLD-OPERAND REGISTER PREFETCH: old chunks 0..3 are loaded into regs
//     BEFORE the fresh-flag wait (old data is own-layer, >=1 hop old,
//     barrier-bounded -> flags effectively always set); old 4..7 reuse the
//     fresh window after the fresh stream drains. Consumption order is
//     unchanged (fresh kk 0..31 then old kk 32..63) -> MFMA sequence per
//     wave is BIT-IDENTICAL to r11 (absmax=2.441e-4 invariant).
//   * applies to L1 prefix (s>=2) and both decode hop types; L0 prefix
//     already has this shape (ungated XH prefetch).
// Everything else (chunk-granular per-wave gating, full-line discovery,
// r11 block epilogue + flags, LDS-resident weights, post-loop y) = r11.
// ============================================================================

typedef _Float16 half_t;
typedef _Float16 half8 __attribute__((ext_vector_type(8)));
typedef float float4v __attribute__((ext_vector_type(4)));
typedef int int32x4_t __attribute__((ext_vector_type(4)));
typedef float float32x4_t __attribute__((ext_vector_type(4)));

__device__ float32x4_t llvm_amdgcn_raw_buffer_load_fp32x4(
    int32x4_t srsrc, int voffset, int soffset, int aux)
    __asm("llvm.amdgcn.raw.buffer.load.v4f32");

#define AUX_SC1 16  // device scope: bypass L1/L2, served by IF$

union SrdU { int32x4_t v; struct { const void* p; unsigned nr, fl; } s; };
__device__ __forceinline__ int32x4_t make_srd(const void* p) {
  SrdU u; u.s.p = p; u.s.nr = 0xFFFFFFFFu; u.s.fl = 0x00020000u; return u.v;
}

// Read 4 group counters device-coherently; bit i set iff p[i] >= 16.
__device__ __forceinline__ unsigned poll4(const int* p) {
  union { float32x4_t f; int i[4]; } u;
  u.f = llvm_amdgcn_raw_buffer_load_fp32x4(make_srd(p), 0, 0, AUX_SC1);
  unsigned m = 0;
  if (u.i[0] >= 16) m |= 1u;
  if (u.i[1] >= 16) m |= 2u;
  if (u.i[2] >= 16) m |= 4u;
  if (u.i[3] >= 16) m |= 8u;
  return m;
}

__device__ __forceinline__ unsigned peek8(const int* f) {
  return poll4(f) | (poll4(f + 4) << 4);
}

// Wave-level wait for group/chunk c; polls the FULL 8-group line each retry
// so any blocked wait also discovers all later groups. Trailing compiler
// barrier pins this chunk's A-load issue below the wait.
__device__ __forceinline__ void wait_chunk(const int* f, int c, unsigned& got) {
  if (!((got >> c) & 1)) {
    for (;;) {
      got |= peek8(f);
      if ((got >> c) & 1) break;
      __builtin_amdgcn_s_sleep(2);
    }
  }
  asm volatile("" ::: "memory");
}

__device__ __forceinline__ void flag_add(int* p) {
  __hip_atomic_fetch_add(p, 1, __ATOMIC_RELAXED, __HIP_MEMORY_SCOPE_AGENT);
}

__device__ __forceinline__ float sigm_(float x) { return 1.0f / (1.0f + __expf(-x)); }
__device__ __forceinline__ float tanh_(float x) {
  float ax = fabsf(x);
  float e = __expf(-2.0f * ax);
  float t = (1.0f - e) / (1.0f + e);
  return x < 0.0f ? -t : t;
}

#define MFMA16(a, b, c) __builtin_amdgcn_mfma_f32_16x16x32_f16(a, b, c, 0, 0, 0)

// ---------------- pipelined chunk streaming ----------------
// A chunk = 128 K (4 kk-iters of MFMA 16x16x32) = 32 KB of fragment-linear A,
// produced exactly by flag-group c (blocks c*16..c*16+15).

__device__ __forceinline__ void issue_chunk(const half_t* __restrict__ A, int c,
                                            int ro, half8 (&a0)[4], half8 (&a1)[4]) {
#pragma unroll
  for (int k4 = 0; k4 < 4; ++k4) {
    const half_t* ap = A + (c * 16 + k4 * 4) * 1024 + ro;
    a0[k4] = *(const half8*)ap;
    a1[k4] = *(const half8*)(ap + 128);
  }
}

__device__ __forceinline__ void consume_chunk(const half8 (&a0)[4],
                                              const half8 (&a1)[4],
                                              const half_t* __restrict__ W, int kk0,
                                              int lq, int lrow, float4v acc[2][2]) {
#pragma unroll
  for (int k4 = 0; k4 < 4; ++k4) {
    const half_t* bp = W + (kk0 + k4) * 1024 + lq * 256 + lrow * 8;
    half8 b0 = *(const half8*)bp;
    half8 b1 = *(const half8*)(bp + 128);
    acc[0][0] = MFMA16(a0[k4], b0, acc[0][0]);
    acc[0][1] = MFMA16(a0[k4], b1, acc[0][1]);
    acc[1][0] = MFMA16(a1[k4], b0, acc[1][0]);
    acc[1][1] = MFMA16(a1[k4], b1, acc[1][1]);
  }
}

template <int NC>
__device__ __forceinline__ void issue_chunks(const half_t* __restrict__ A, int ro,
                                             half8 (&a0)[NC][4], half8 (&a1)[NC][4]) {
#pragma unroll
  for (int c = 0; c < NC; ++c) issue_chunk(A, c, ro, a0[c], a1[c]);
}

template <int NC>
__device__ __forceinline__ void consume_chunks(const half8 (&a0)[NC][4],
                                               const half8 (&a1)[NC][4],
                                               const half_t* __restrict__ W, int kk0,
                                               int lq, int lrow, float4v acc[2][2]) {
#pragma unroll
  for (int c = 0; c < NC; ++c)
    consume_chunk(a0[c], a1[c], W, kk0 + c * 4, lq, lrow, acc);
}

// 8-chunk (K=1024) gated stream: 4-chunk register window, per-wave waits,
// no intra-block barriers.
__device__ __forceinline__ void stream8g(const half_t* __restrict__ A,
                                         const half_t* __restrict__ W, int kk0,
                                         const int* f, unsigned got,
                                         int ro, int lq, int lrow, float4v acc[2][2]) {
  half8 a0[4][4], a1[4][4];
#pragma unroll
  for (int c = 0; c < 4; ++c) {
    wait_chunk(f, c, got);
    issue_chunk(A, c, ro, a0[c], a1[c]);
  }
#pragma unroll
  for (int c = 0; c < 8; ++c) {
    consume_chunk(a0[c & 3], a1[c & 3], W, kk0 + c * 4, lq, lrow, acc);
    if (c < 4) {
      wait_chunk(f, c + 4, got);
      issue_chunk(A, c + 4, ro, a0[c & 3], a1[c & 3]);
    }
  }
}

// Fresh+old hop with OLD-OPERAND REGISTER PREFETCH.
// Old (own-layer, >=1 hop old) is confirmed and chunks 0..3 are issued into
// prefetch regs BEFORE the fresh gated stream; old 4..7 reuse the fresh
// window after it drains. Consumption order: fresh kk 0..31 then old
// kk 32..63 -- bit-identical MFMA sequence to r11.
__device__ __forceinline__ void hop_fo(
    const half_t* __restrict__ Afresh, const half_t* __restrict__ Aold,
    const half_t* __restrict__ W, const int* fF, const int* fO,
    int ro, int lq, int lrow, float4v acc[2][2]) {
  // confirm all 8 old chunks (rarely blocks)
  unsigned gotO = peek8(fO);
  if (gotO != 0xFFu) {
#pragma unroll
    for (int c = 0; c < 8; ++c) wait_chunk(fO, c, gotO);
  }
  asm volatile("" ::: "memory");
  // prefetch old 0..3: loads fly under the fresh wait + fresh stream
  half8 p0[4][4], p1[4][4];
#pragma unroll
  for (int c = 0; c < 4; ++c) issue_chunk(Aold, c, ro, p0[c], p1[c]);
  // gated fresh stream (kk 0..31) through window w
  half8 w0[4][4], w1[4][4];
  unsigned gotF = 0u;
#pragma unroll
  for (int c = 0; c < 4; ++c) {
    wait_chunk(fF, c, gotF);
    issue_chunk(Afresh, c, ro, w0[c], w1[c]);
  }
#pragma unroll
  for (int c = 0; c < 8; ++c) {
    consume_chunk(w0[c & 3], w1[c & 3], W, c * 4, lq, lrow, acc);
    if (c < 4) {
      wait_chunk(fF, c + 4, gotF);
      issue_chunk(Afresh, c + 4, ro, w0[c & 3], w1[c & 3]);
    }
  }
  // old tail 4..7 into the now-dead fresh window; consume old ascending
#pragma unroll
  for (int c = 0; c < 4; ++c) issue_chunk(Aold, c + 4, ro, w0[c], w1[c]);
#pragma unroll
  for (int c = 0; c < 4; ++c)
    consume_chunk(p0[c], p1[c], W, 32 + c * 4, lq, lrow, acc);
#pragma unroll
  for (int c = 0; c < 4; ++c)
    consume_chunk(w0[c], w1[c], W, 48 + c * 4, lq, lrow, acc);
}

// L0-prefix stream: ungated XH (2 chunks, kk 0..7) issued first and consumed
// while the gated H prologue loads are in flight; H covers kk 8..39.
__device__ __forceinline__ void stream_l0p(const half_t* __restrict__ XHs,
                                           const half_t* __restrict__ A,
                                           const half_t* __restrict__ W,
                                           const int* f, int ro, int lq, int lrow,
                                           float4v acc[2][2]) {
  half8 xa0[2][4], xa1[2][4];
  issue_chunks<2>(XHs, ro, xa0, xa1);
  unsigned got = peek8(f);
  half8 a0[4][4], a1[4][4];
#pragma unroll
  for (int c = 0; c < 4; ++c) {
    wait_chunk(f, c, got);
    issue_chunk(A, c, ro, a0[c], a1[c]);
  }
  consume_chunk(xa0[0], xa1[0], W, 0, lq, lrow, acc);
  consume_chunk(xa0[1], xa1[1], W, 4, lq, lrow, acc);
#pragma unroll
  for (int c = 0; c < 8; ++c) {
    consume_chunk(a0[c & 3], a1[c & 3], W, 8 + c * 4, lq, lrow, acc);
    if (c < 4) {
      wait_chunk(f, c + 4, got);
      issue_chunk(A, c + 4, ro, a0[c & 3], a1[c & 3]);
    }
  }
}

// Cell epilogue for a [128 x 32] gate tile (8 units x 4 gates per col group).
// c persists in 4 VGPRs; h staged via 2 KB LDS tile, stored sc1 to ring slot.
// (r11 block version, verbatim.)
__device__ __forceinline__ void epi_gates(
    float4v acc[2][2], int tile, const float* __restrict__ biasArr,
    float c[2][2], half_t* hTile, half_t* __restrict__ hDst, int tid) {
  const int l = tid & 63, rg = tid >> 6;
  const int lrow = l & 15, lq = l >> 4, q = l & 3, a = lrow >> 2;
  __syncthreads();  // reconverge slipped waves before LDS staging
#pragma unroll
  for (int m = 0; m < 2; ++m)
#pragma unroll
    for (int nf = 0; nf < 2; ++nf) {
      const float bias = biasArr[tile * 32 + nf * 16 + lrow];
      float gi = 0.f, gf = 0.f, gg = 0.f, go = 0.f;
#pragma unroll
      for (int r = 0; r < 4; ++r) {
        float x = acc[m][nf][r] + bias;
        float t1 = __shfl_xor(x, 1);
        float t2 = __shfl_xor(x, 2);
        float t3 = __shfl_xor(x, 3);
        if (r == q) {
          gi = (q == 0) ? x : (q == 1 ? t1 : (q == 2 ? t2 : t3));
          gf = (q == 1) ? x : (q == 0 ? t1 : (q == 3 ? t2 : t3));
          gg = (q == 2) ? x : (q == 3 ? t1 : (q == 0 ? t2 : t3));
          go = (q == 3) ? x : (q == 2 ? t1 : (q == 1 ? t2 : t3));
        }
      }
      const int row = rg * 32 + m * 16 + lq * 4 + q;
      const int ju = nf * 4 + a;
      float iv = sigm_(gi), fv = sigm_(gf), gv = tanh_(gg), ov = sigm_(go);
      float cnew = fv * c[m][nf] + iv * gv;
      c[m][nf] = cnew;
      hTile[row * 8 + ju] = (half_t)(ov * tanh_(cnew));
    }
  __syncthreads();
  if (tid < 128) {
    const unsigned long long* s = (const unsigned long long*)(hTile + tid * 8);
    unsigned long long v0 = s[0], v1 = s[1];
    unsigned long long* d = (unsigned long long*)(hDst + tid * 8);
    __hip_atomic_store(d, v0, __ATOMIC_RELAXED, __HIP_MEMORY_SCOPE_AGENT);
    __hip_atomic_store(d + 1, v1, __ATOMIC_RELAXED, __HIP_MEMORY_SCOPE_AGENT);
  }
}

__device__ __forceinline__ void epi_y(
    float4v acc[2][2], int ytile, int i, const float* __restrict__ biasY,
    float* __restrict__ out, int tid) {
  const int l = tid & 63, rg = tid >> 6;
  const int lrow = l & 15, lq = l >> 4;
#pragma unroll
  for (int m = 0; m < 2; ++m)
#pragma unroll
    for (int nf = 0; nf < 2; ++nf) {
      const int d = ytile * 32 + nf * 16 + lrow;
      const float b = biasY[d];
#pragma unroll
      for (int r = 0; r < 4; ++r) {
        const int row = rg * 32 + m * 16 + lq * 4 + r;
        out[(long)row * 15360 + i * 256 + d] = acc[m][nf][r] + b;
      }
    }
}

__device__ __forceinline__ void loadW(const half_t* __restrict__ src,
                                      half_t* dst, int halves, int tid) {
  for (int i = tid * 8; i < halves; i += 2048)
    *(uint4*)(dst + i) = *(const uint4*)(src + i);
}

#define ZACC2 float4v acc[2][2]; { float4v z = {0.f, 0.f, 0.f, 0.f}; \
  acc[0][0] = z; acc[0][1] = z; acc[1][0] = z; acc[1][1] = z; }

__global__ void __launch_bounds__(256, 1) k_lstm(
    const half_t* __restrict__ S0, const half_t* __restrict__ S1,
    const half_t* __restrict__ SD, const half_t* __restrict__ SY,
    const half_t* __restrict__ XH,
    half_t* __restrict__ H0, half_t* __restrict__ H1,
    const float* __restrict__ B0P, const float* __restrict__ B1P,
    const float* __restrict__ BD0P, float* __restrict__ out, int* FLGB) {
  __shared__ char smem[133120];  // 128 KB W (persistent) + 2 KB hTile
  half_t* ldsW = (half_t*)smem;
  half_t* hTile = (half_t*)(smem + 131072);
  const int w = blockIdx.x, tid = threadIdx.x;
  const int l = tid & 63, rg = tid >> 6;
  const int lrow = l & 15, lq = l >> 4;
  const int ro = (rg * 32 + lrow) * 8 + lq * 1024;
  float c2[2][2] = {{0.f, 0.f}, {0.f, 0.f}};
#define SLOTP(base, idx) ((base) + (long)(idx) * 131072)
// flag record for (step, layer) replica rg: 32 ints (128 B), counters to 16
#define FREC(s, lay, rr) (FLGB + ((((s) * 2 + (lay)) * 4 + (rr)) << 5))

  if (w < 128) {  // ============ L0 prefix + decode cell0 ============
    const int g = w >> 4;
    loadW(S0 + (long)w * 40960, ldsW, 40960, tid);
    __syncthreads();
    {  // s = 0: H0[0] == 0 -> XH contribution only
      ZACC2;
      half8 xa0[2][4], xa1[2][4];
      issue_chunks<2>(XH, ro, xa0, xa1);
      consume_chunks<2>(xa0, xa1, ldsW, 0, lq, lrow, acc);
      epi_gates(acc, w, B0P, c2, hTile, SLOTP(H0, 1) + w * 1024, tid);
      __syncthreads();  // drain sc1 h-stores before flagging
      if ((tid & 63) == 0) flag_add(FREC(0, 0, rg) + g);
    }
    for (int s = 1; s < 256; ++s) {
      ZACC2;
      stream_l0p(XH + (long)s * 32768, SLOTP(H0, s), ldsW, FREC(s - 1, 0, rg),
                 ro, lq, lrow, acc);
      epi_gates(acc, w, B0P, c2, hTile, SLOTP(H0, s + 1) + w * 1024, tid);
      __syncthreads();
      if ((tid & 63) == 0) flag_add(FREC(s, 0, rg) + g);
    }
    __syncthreads();
    loadW(SD + (long)w * 65536, ldsW, 65536, tid);  // swap in Weff|Whh0
    __syncthreads();
    for (int i = 0; i < 59; ++i) {
      ZACC2;
      // fresh H1[256+i] -> Weff (kk 0..31); old H0[256+i] -> Whh0 (kk 32..63)
      hop_fo(SLOTP(H1, 256 + i), SLOTP(H0, 256 + i), ldsW,
             FREC(256 + i, 1, rg), FREC(255 + i, 0, rg), ro, lq, lrow, acc);
      epi_gates(acc, w, BD0P, c2, hTile, SLOTP(H0, 257 + i) + w * 1024, tid);
      __syncthreads();
      if ((tid & 63) == 0) flag_add(FREC(256 + i, 0, rg) + g);
    }
  } else {  // ============ L1 prefix + decode cell1 ============
    const int bw = w - 128, g = bw >> 4;
    loadW(S1 + (long)bw * 65536, ldsW, 65536, tid);
    __syncthreads();
    {  // s = 1: H1[0] == 0 -> only fresh H0[1] stream (kk 0..31)
      ZACC2;
      stream8g(SLOTP(H0, 1), ldsW, 0, FREC(0, 0, rg), 0u, ro, lq, lrow, acc);
      epi_gates(acc, bw, B1P, c2, hTile, SLOTP(H1, 1) + bw * 1024, tid);
      __syncthreads();
      if ((tid & 63) == 0) flag_add(FREC(1, 1, rg) + g);
    }
    for (int s = 2; s <= 256; ++s) {
      ZACC2;
      // fresh H0[s] -> Wih1 (kk 0..31); old H1[s-1] -> Whh1 (kk 32..63)
      hop_fo(SLOTP(H0, s), SLOTP(H1, s - 1), ldsW,
             FREC(s - 1, 0, rg), FREC(s - 1, 1, rg), ro, lq, lrow, acc);
      epi_gates(acc, bw, B1P, c2, hTile, SLOTP(H1, s) + bw * 1024, tid);
      __syncthreads();
      if ((tid & 63) == 0) flag_add(FREC(s, 1, rg) + g);
    }
    for (int i = 0; i < 59; ++i) {
      ZACC2;
      // fresh H0[257+i] -> Wih1 (kk 0..31); old H1[256+i] -> Whh1 (kk 32..63)
      hop_fo(SLOTP(H0, 257 + i), SLOTP(H1, 256 + i), ldsW,
             FREC(256 + i, 0, rg), FREC(256 + i, 1, rg), ro, lq, lrow, acc);
      epi_gates(acc, bw, B1P, c2, hTile, SLOTP(H1, 257 + i) + bw * 1024, tid);
      __syncthreads();
      if ((tid & 63) == 0) flag_add(FREC(257 + i, 1, rg) + g);
    }
  }

  // ---- post-loop: y[i] = H1[256+i] @ Wlin^T + b, i = 0..59, 8 col-tiles ----
  // 480 tile-jobs over 256 blocks; off the recurrence chain entirely.
  for (int j = w; j < 480; j += 256) {
    const int i = j >> 3, t = j & 7;
    ZACC2;
    const int* f = FREC(256 + i, 1, rg);
    stream8g(SLOTP(H1, 256 + i), SY + (long)t * 32768, 0, f, peek8(f),
             ro, lq, lrow, acc);
    epi_y(acc, t, i, BD0P + 4096, out, tid);
  }
#undef FREC
#undef SLOTP
}

// ======================= setup kernels (round-5 verbatim) ===================

__global__ void k_cvt_x(const float* __restrict__ x, half_t* __restrict__ XH) {
  int idx = blockIdx.x * 256 + threadIdx.x;  // 1,048,576 total
  int t = idx >> 12;
  int kb = (idx >> 7) & 31;
  int r = idx & 127;
  const float* src = x + ((long)((r << 8) + t)) * 256 + kb * 8;
  float4 v0 = *(const float4*)src;
  float4 v1 = *(const float4*)(src + 4);
  half_t tmp[8] = {(half_t)v0.x, (half_t)v0.y, (half_t)v0.z, (half_t)v0.w,
                   (half_t)v1.x, (half_t)v1.y, (half_t)v1.z, (half_t)v1.w};
  *(uint4*)(XH + (long)t * 32768 + kb * 1024 + r * 8) = *(const uint4*)tmp;
}

__global__ void k_pack32(const float* __restrict__ A, int KA,
                         const float* __restrict__ Bsrc,
                         half_t* __restrict__ dst, int KT32, int skipA) {
  int idx = blockIdx.x * 256 + threadIdx.x;
  int nn = idx & 31;
  int lq = (idx >> 5) & 3;
  int t2 = idx >> 7;
  int kk = t2 % KT32;
  int tile = t2 / KT32;
  if (tile >= 128) return;
  int k = kk * 32 + lq * 8;
  int rp = tile * 32 + nn;
  int r = ((rp & 3) << 10) + (rp >> 2);
  const float* src;
  if (k < KA) {
    if (skipA) return;
    src = A + (long)r * KA + k;
  } else {
    src = Bsrc + (long)r * 1024 + (k - KA);
  }
  float4 v0 = *(const float4*)src;
  float4 v1 = *(const float4*)(src + 4);
  half_t tmp[8] = {(half_t)v0.x, (half_t)v0.y, (half_t)v0.z, (half_t)v0.w,
                   (half_t)v1.x, (half_t)v1.y, (half_t)v1.z, (half_t)v1.w};
  *(uint4*)(dst + (long)tile * (KT32 * 1024) + kk * 1024 + lq * 256 + nn * 8) =
      *(const uint4*)tmp;
}

__global__ void k_pack_y32(const float* __restrict__ Wlin,
                           half_t* __restrict__ SY) {
  int idx = blockIdx.x * 256 + threadIdx.x;  // 32768 total
  int nn = idx & 31;
  int lq = (idx >> 5) & 3;
  int kk = (idx >> 7) & 31;
  int tile = idx >> 12;
  int d = tile * 32 + nn;
  int k = kk * 32 + lq * 8;
  const float* src = Wlin + (long)d * 1024 + k;
  float4 v0 = *(const float4*)src;
  float4 v1 = *(const float4*)(src + 4);
  half_t tmp[8] = {(half_t)v0.x, (half_t)v0.y, (half_t)v0.z, (half_t)v0.w,
                   (half_t)v1.x, (half_t)v1.y, (half_t)v1.z, (half_t)v1.w};
  *(uint4*)(SY + (long)tile * 32768 + kk * 1024 + lq * 256 + nn * 8) =
      *(const uint4*)tmp;
}

__global__ void k_bias_simple(const float* bi0, const float* bh0,
                              const float* bi1, const float* bh1,
                              const float* blin, float* b0p, float* b1p,
                              float* bD0p) {
  int rp = blockIdx.x * blockDim.x + threadIdx.x;
  if (rp < 4096) {
    int r = ((rp & 3) << 10) + (rp >> 2);
    b0p[rp] = bi0[r] + bh0[r];
    b1p[rp] = bi1[r] + bh1[r];
  } else if (rp < 4352) {
    bD0p[rp] = blin[rp - 4096];
  }
}

__global__ void k_bias_dot(const float* __restrict__ Wih0,
                           const float* __restrict__ blin,
                           const float* __restrict__ bi0,
                           const float* __restrict__ bh0,
                           float* __restrict__ bD0p) {
  int wv = threadIdx.x >> 6, l = threadIdx.x & 63;
  int r = blockIdx.x * 4 + wv;
  float s = 0.f;
#pragma unroll
  for (int c = 0; c < 4; ++c) s += Wih0[r * 256 + c * 64 + l] * blin[c * 64 + l];
#pragma unroll
  for (int o = 32; o >= 1; o >>= 1) s += __shfl_xor(s, o);
  if (l == 0) {
    int rp = ((r & 1023) << 2) | (r >> 10);
    bD0p[rp] = bi0[r] + bh0[r] + s;
  }
}

__global__ void k_weff(const float* __restrict__ Wih0,
                       const float* __restrict__ Wlin,
                       half_t* __restrict__ SD) {
  __shared__ float At[64][65];
  __shared__ float Bt[64][65];
  const int rt = blockIdx.x, jt = blockIdx.y;
  const int tid = threadIdx.x;
  const int tx = tid & 15, ty = tid >> 4;
  float acc[4][4] = {};
  for (int k0 = 0; k0 < 256; k0 += 64) {
    __syncthreads();
#pragma unroll
    for (int i = 0; i < 16; ++i) {
      int lin = tid + 256 * i;
      int rr = lin >> 6, kk = lin & 63;
      At[rr][kk] = Wih0[(rt * 64 + rr) * 256 + k0 + kk];
      Bt[rr][kk] = Wlin[(k0 + rr) * 1024 + jt * 64 + kk];
    }
    __syncthreads();
    for (int kk = 0; kk < 64; ++kk) {
      float a[4], b[4];
#pragma unroll
      for (int i = 0; i < 4; ++i) a[i] = At[ty * 4 + i][kk];
#pragma unroll
      for (int i = 0; i < 4; ++i) b[i] = Bt[kk][tx * 4 + i];
#pragma unroll
      for (int i = 0; i < 4; ++i)
#pragma unroll
        for (int jx = 0; jx < 4; ++jx) acc[i][jx] += a[i] * b[jx];
    }
  }
#pragma unroll
  for (int i = 0; i < 4; ++i) {
    int r = rt * 64 + ty * 4 + i;
    int rp = ((r & 1023) << 2) | (r >> 10);
    int tile = rp >> 5, nn = rp & 31;
#pragma unroll
    for (int jx = 0; jx < 4; ++jx) {
      int j = jt * 64 + tx * 4 + jx;
      SD[(long)tile * 65536 + (j >> 5) * 1024 + ((j >> 3) & 3) * 256 + nn * 8 +
         (j & 7)] = (half_t)acc[i][jx];
    }
  }
}

// ======================= launch =======================

extern "C" void kernel_launch(void* const* d_in, const int* in_sizes, int n_in,
                              void* d_out, int out_size, void* d_ws, size_t ws_size,
                              hipStream_t stream) {
  (void)in_sizes; (void)n_in; (void)out_size; (void)ws_size;
  const float* x    = (const float*)d_in[0];
  const float* Wih0 = (const float*)d_in[1];
  const float* Whh0 = (const float*)d_in[2];
  const float* bi0  = (const float*)d_in[3];
  const float* bh0  = (const float*)d_in[4];
  const float* Wih1 = (const float*)d_in[5];
  const float* Whh1 = (const float*)d_in[6];
  const float* bi1  = (const float*)d_in[7];
  const float* bh1  = (const float*)d_in[8];
  const float* Wlin = (const float*)d_in[9];
  const float* blin = (const float*)d_in[10];
  float* out = (float*)d_out;
  char* ws = (char*)d_ws;

  half_t* S0  = (half_t*)(ws + 0);         // 128 x 40960 x 2 = 10 MB
  half_t* S1  = (half_t*)(ws + 10485760);  // 128 x 65536 x 2 = 16 MB
  half_t* SD  = (half_t*)(ws + 27262976);  // 16 MB
  half_t* SY  = (half_t*)(ws + 44040192);  // 512 KB
  half_t* XH  = (half_t*)(ws + 44564480);  // 16 MB
  float*  B0P = (float*)(ws + 61341696);   // 16 KB
  float*  B1P = (float*)(ws + 61358080);   // 16 KB
  float*  BD0P= (float*)(ws + 61374464);   // 17408 B
  half_t* H0  = (half_t*)(ws + 61432320);  // ring: 320 x 256 KB = 80 MB
  half_t* H1  = (half_t*)(ws + 145318400); // ring: 320 x 256 KB = 80 MB
  // flag counters (x4 wave replicas) in the spare tail slots of the H1 ring
  // (slots 316..319 never written by the recurrence): 2560 lines x 128 B
  int*    FLGB= (int*)(ws + 145318400 + (long)316 * 262144);  // 228,155,904

  hipMemsetAsync(FLGB, 0, 327680, stream);     // all flag records
  hipMemsetAsync(H0, 0, 262144, stream);       // H0 slot 0 (safety; unused)
  hipMemsetAsync(H1, 0, 262144, stream);       // H1 slot 0 (safety; unused)

  k_cvt_x<<<4096, 256, 0, stream>>>(x, XH);
  k_bias_simple<<<17, 256, 0, stream>>>(bi0, bh0, bi1, bh1, blin, B0P, B1P, BD0P);
  k_bias_dot<<<1024, 256, 0, stream>>>(Wih0, blin, bi0, bh0, BD0P);
  k_pack32<<<2560, 256, 0, stream>>>(Wih0, 256, Whh0, S0, 40, 0);
  k_pack32<<<4096, 256, 0, stream>>>(Wih1, 1024, Whh1, S1, 64, 0);
  k_pack32<<<4096, 256, 0, stream>>>(nullptr, 1024, Whh0, SD, 64, 1);
  k_pack_y32<<<128, 256, 0, stream>>>(Wlin, SY);
  k_weff<<<dim3(64, 16), 256, 0, stream>>>(Wih0, Wlin, SD);

  k_lstm<<<256, 256, 0, stream>>>(S0, S1, SD, SY, XH, H0, H1,
                                  B0P, B1P, BD0P, out, FLGB);
}

// Round 10
// 4597.758 us; speedup vs baseline: 2.1489x; 1.2225x over previous
//
#include <hip/hip_runtime.h>
#include <hip/hip_bf16.h>
#include <cstdint>

// ============================================================================
// 2-layer LSTM prefix + 59-step decode, persistent kernel, round 15.
// Round-15 (r14 post-mortem: old-prefetch regressed +20% -- load reorder put
// old traffic AHEAD of the critical fresh loads. r9~r10~r11 at ~4650 proves
// intra-hop scheduling is not the limiter; hop cost is handoff-pipeline
// latency. REVERT to r11 wholesale; single provable redundancy removed):
//   * DROP the epilogue ENTRY barrier. r11 had 3 barriers/hop:
//     SYNC3(s-1) -> streams -> SYNC1 -> write hTile -> SYNC2 -> read+store
//     -> SYNC3. The WAR hazard SYNC1 guards (hop-s writes vs hop-(s-1)
//     reads of hTile) is already eliminated by SYNC3 of the previous hop.
//     2 barriers/hop remain (write->read, and store-drain-before-flag).
//   * Everything else is r11 VERBATIM: chunk-granular per-wave gating,
//     full-line flag discovery, fresh-first ascending-kk accumulation
//     (absmax=2.441e-4 invariant), LDS-resident weights, block epilogue,
//     x4 flag replicas, post-loop y.
// ============================================================================

typedef _Float16 half_t;
typedef _Float16 half8 __attribute__((ext_vector_type(8)));
typedef float float4v __attribute__((ext_vector_type(4)));
typedef int int32x4_t __attribute__((ext_vector_type(4)));
typedef float float32x4_t __attribute__((ext_vector_type(4)));

__device__ float32x4_t llvm_amdgcn_raw_buffer_load_fp32x4(
    int32x4_t srsrc, int voffset, int soffset, int aux)
    __asm("llvm.amdgcn.raw.buffer.load.v4f32");

#define AUX_SC1 16  // device scope: bypass L1/L2, served by IF$

union SrdU { int32x4_t v; struct { const void* p; unsigned nr, fl; } s; };
__device__ __forceinline__ int32x4_t make_srd(const void* p) {
  SrdU u; u.s.p = p; u.s.nr = 0xFFFFFFFFu; u.s.fl = 0x00020000u; return u.v;
}

// Read 4 group counters device-coherently; bit i set iff p[i] >= 16.
__device__ __forceinline__ unsigned poll4(const int* p) {
  union { float32x4_t f; int i[4]; } u;
  u.f = llvm_amdgcn_raw_buffer_load_fp32x4(make_srd(p), 0, 0, AUX_SC1);
  unsigned m = 0;
  if (u.i[0] >= 16) m |= 1u;
  if (u.i[1] >= 16) m |= 2u;
  if (u.i[2] >= 16) m |= 4u;
  if (u.i[3] >= 16) m |= 8u;
  return m;
}

__device__ __forceinline__ unsigned peek8(const int* f) {
  return poll4(f) | (poll4(f + 4) << 4);
}

// Wave-level wait for group/chunk c; polls the FULL 8-group line each retry
// so any blocked wait also discovers all later groups. Trailing compiler
// barrier pins this chunk's A-load issue below the wait.
__device__ __forceinline__ void wait_chunk(const int* f, int c, unsigned& got) {
  if (!((got >> c) & 1)) {
    for (;;) {
      got |= peek8(f);
      if ((got >> c) & 1) break;
      __builtin_amdgcn_s_sleep(2);
    }
  }
  asm volatile("" ::: "memory");
}

__device__ __forceinline__ void flag_add(int* p) {
  __hip_atomic_fetch_add(p, 1, __ATOMIC_RELAXED, __HIP_MEMORY_SCOPE_AGENT);
}

__device__ __forceinline__ float sigm_(float x) { return 1.0f / (1.0f + __expf(-x)); }
__device__ __forceinline__ float tanh_(float x) {
  float ax = fabsf(x);
  float e = __expf(-2.0f * ax);
  float t = (1.0f - e) / (1.0f + e);
  return x < 0.0f ? -t : t;
}

#define MFMA16(a, b, c) __builtin_amdgcn_mfma_f32_16x16x32_f16(a, b, c, 0, 0, 0)

// ---------------- pipelined chunk streaming ----------------
// A chunk = 128 K (4 kk-iters of MFMA 16x16x32) = 32 KB of fragment-linear A,
// produced exactly by flag-group c (blocks c*16..c*16+15).

__device__ __forceinline__ void issue_chunk(const half_t* __restrict__ A, int c,
                                            int ro, half8 (&a0)[4], half8 (&a1)[4]) {
#pragma unroll
  for (int k4 = 0; k4 < 4; ++k4) {
    const half_t* ap = A + (c * 16 + k4 * 4) * 1024 + ro;
    a0[k4] = *(const half8*)ap;
    a1[k4] = *(const half8*)(ap + 128);
  }
}

__device__ __forceinline__ void consume_chunk(const half8 (&a0)[4],
                                              const half8 (&a1)[4],
                                              const half_t* __restrict__ W, int kk0,
                                              int lq, int lrow, float4v acc[2][2]) {
#pragma unroll
  for (int k4 = 0; k4 < 4; ++k4) {
    const half_t* bp = W + (kk0 + k4) * 1024 + lq * 256 + lrow * 8;
    half8 b0 = *(const half8*)bp;
    half8 b1 = *(const half8*)(bp + 128);
    acc[0][0] = MFMA16(a0[k4], b0, acc[0][0]);
    acc[0][1] = MFMA16(a0[k4], b1, acc[0][1]);
    acc[1][0] = MFMA16(a1[k4], b0, acc[1][0]);
    acc[1][1] = MFMA16(a1[k4], b1, acc[1][1]);
  }
}

template <int NC>
__device__ __forceinline__ void issue_chunks(const half_t* __restrict__ A, int ro,
                                             half8 (&a0)[NC][4], half8 (&a1)[NC][4]) {
#pragma unroll
  for (int c = 0; c < NC; ++c) issue_chunk(A, c, ro, a0[c], a1[c]);
}

template <int NC>
__device__ __forceinline__ void consume_chunks(const half8 (&a0)[NC][4],
                                               const half8 (&a1)[NC][4],
                                               const half_t* __restrict__ W, int kk0,
                                               int lq, int lrow, float4v acc[2][2]) {
#pragma unroll
  for (int c = 0; c < NC; ++c)
    consume_chunk(a0[c], a1[c], W, kk0 + c * 4, lq, lrow, acc);
}

// 8-chunk (K=1024) gated stream: 4-chunk register window, per-wave waits,
// no intra-block barriers.
__device__ __forceinline__ void stream8g(const half_t* __restrict__ A,
                                         const half_t* __restrict__ W, int kk0,
                                         const int* f, unsigned got,
                                         int ro, int lq, int lrow, float4v acc[2][2]) {
  half8 a0[4][4], a1[4][4];
#pragma unroll
  for (int c = 0; c < 4; ++c) {
    wait_chunk(f, c, got);
    issue_chunk(A, c, ro, a0[c], a1[c]);
  }
#pragma unroll
  for (int c = 0; c < 8; ++c) {
    consume_chunk(a0[c & 3], a1[c & 3], W, kk0 + c * 4, lq, lrow, acc);
    if (c < 4) {
      wait_chunk(f, c + 4, got);
      issue_chunk(A, c + 4, ro, a0[c & 3], a1[c & 3]);
    }
  }
}

// L0-prefix stream: ungated XH (2 chunks, kk 0..7) issued first and consumed
// while the gated H prologue loads are in flight; H covers kk 8..39.
__device__ __forceinline__ void stream_l0p(const half_t* __restrict__ XHs,
                                           const half_t* __restrict__ A,
                                           const half_t* __restrict__ W,
                                           const int* f, int ro, int lq, int lrow,
                                           float4v acc[2][2]) {
  half8 xa0[2][4], xa1[2][4];
  issue_chunks<2>(XHs, ro, xa0, xa1);
  unsigned got = peek8(f);
  half8 a0[4][4], a1[4][4];
#pragma unroll
  for (int c = 0; c < 4; ++c) {
    wait_chunk(f, c, got);
    issue_chunk(A, c, ro, a0[c], a1[c]);
  }
  consume_chunk(xa0[0], xa1[0], W, 0, lq, lrow, acc);
  consume_chunk(xa0[1], xa1[1], W, 4, lq, lrow, acc);
#pragma unroll
  for (int c = 0; c < 8; ++c) {
    consume_chunk(a0[c & 3], a1[c & 3], W, 8 + c * 4, lq, lrow, acc);
    if (c < 4) {
      wait_chunk(f, c + 4, got);
      issue_chunk(A, c + 4, ro, a0[c & 3], a1[c & 3]);
    }
  }
}

// Cell epilogue for a [128 x 32] gate tile (8 units x 4 gates per col group).
// c persists in 4 VGPRs; h staged via 2 KB LDS tile, stored sc1 to ring slot.
// r15: NO entry barrier -- the previous hop's trailing __syncthreads already
// guarantees all hTile reads completed before any wave reaches these writes.
__device__ __forceinline__ void epi_gates(
    float4v acc[2][2], int tile, const float* __restrict__ biasArr,
    float c[2][2], half_t* hTile, half_t* __restrict__ hDst, int tid) {
  const int l = tid & 63, rg = tid >> 6;
  const int lrow = l & 15, lq = l >> 4, q = l & 3, a = lrow >> 2;
#pragma unroll
  for (int m = 0; m < 2; ++m)
#pragma unroll
    for (int nf = 0; nf < 2; ++nf) {
      const float bias = biasArr[tile * 32 + nf * 16 + lrow];
      float gi = 0.f, gf = 0.f, gg = 0.f, go = 0.f;
#pragma unroll
      for (int r = 0; r < 4; ++r) {
        float x = acc[m][nf][r] + bias;
        float t1 = __shfl_xor(x, 1);
        float t2 = __shfl_xor(x, 2);
        float t3 = __shfl_xor(x, 3);
        if (r == q) {
          gi = (q == 0) ? x : (q == 1 ? t1 : (q == 2 ? t2 : t3));
          gf = (q == 1) ? x : (q == 0 ? t1 : (q == 3 ? t2 : t3));
          gg = (q == 2) ? x : (q == 3 ? t1 : (q == 0 ? t2 : t3));
          go = (q == 3) ? x : (q == 2 ? t1 : (q == 1 ? t2 : t3));
        }
      }
      const int row = rg * 32 + m * 16 + lq * 4 + q;
      const int ju = nf * 4 + a;
      float iv = sigm_(gi), fv = sigm_(gf), gv = tanh_(gg), ov = sigm_(go);
      float cnew = fv * c[m][nf] + iv * gv;
      c[m][nf] = cnew;
      hTile[row * 8 + ju] = (half_t)(ov * tanh_(cnew));
    }
  __syncthreads();  // write -> read ordering for the cross-wave staging
  if (tid < 128) {
    const unsigned long long* s = (const unsigned long long*)(hTile + tid * 8);
    unsigned long long v0 = s[0], v1 = s[1];
    unsigned long long* d = (unsigned long long*)(hDst + tid * 8);
    __hip_atomic_store(d, v0, __ATOMIC_RELAXED, __HIP_MEMORY_SCOPE_AGENT);
    __hip_atomic_store(d + 1, v1, __ATOMIC_RELAXED, __HIP_MEMORY_SCOPE_AGENT);
  }
}

__device__ __forceinline__ void epi_y(
    float4v acc[2][2], int ytile, int i, const float* __restrict__ biasY,
    float* __restrict__ out, int tid) {
  const int l = tid & 63, rg = tid >> 6;
  const int lrow = l & 15, lq = l >> 4;
#pragma unroll
  for (int m = 0; m < 2; ++m)
#pragma unroll
    for (int nf = 0; nf < 2; ++nf) {
      const int d = ytile * 32 + nf * 16 + lrow;
      const float b = biasY[d];
#pragma unroll
      for (int r = 0; r < 4; ++r) {
        const int row = rg * 32 + m * 16 + lq * 4 + r;
        out[(long)row * 15360 + i * 256 + d] = acc[m][nf][r] + b;
      }
    }
}

__device__ __forceinline__ void loadW(const half_t* __restrict__ src,
                                      half_t* dst, int halves, int tid) {
  for (int i = tid * 8; i < halves; i += 2048)
    *(uint4*)(dst + i) = *(const uint4*)(src + i);
}

#define ZACC2 float4v acc[2][2]; { float4v z = {0.f, 0.f, 0.f, 0.f}; \
  acc[0][0] = z; acc[0][1] = z; acc[1][0] = z; acc[1][1] = z; }

__global__ void __launch_bounds__(256, 1) k_lstm(
    const half_t* __restrict__ S0, const half_t* __restrict__ S1,
    const half_t* __restrict__ SD, const half_t* __restrict__ SY,
    const half_t* __restrict__ XH,
    half_t* __restrict__ H0, half_t* __restrict__ H1,
    const float* __restrict__ B0P, const float* __restrict__ B1P,
    const float* __restrict__ BD0P, float* __restrict__ out, int* FLGB) {
  __shared__ char smem[133120];  // 128 KB W (persistent) + 2 KB hTile
  half_t* ldsW = (half_t*)smem;
  half_t* hTile = (half_t*)(smem + 131072);
  const int w = blockIdx.x, tid = threadIdx.x;
  const int l = tid & 63, rg = tid >> 6;
  const int lrow = l & 15, lq = l >> 4;
  const int ro = (rg * 32 + lrow) * 8 + lq * 1024;
  float c2[2][2] = {{0.f, 0.f}, {0.f, 0.f}};
#define SLOTP(base, idx) ((base) + (long)(idx) * 131072)
// flag record for (step, layer) replica rg: 32 ints (128 B), counters to 16
#define FREC(s, lay, rr) (FLGB + ((((s) * 2 + (lay)) * 4 + (rr)) << 5))

  if (w < 128) {  // ============ L0 prefix + decode cell0 ============
    const int g = w >> 4;
    loadW(S0 + (long)w * 40960, ldsW, 40960, tid);
    __syncthreads();
    {  // s = 0: H0[0] == 0 -> XH contribution only
      ZACC2;
      half8 xa0[2][4], xa1[2][4];
      issue_chunks<2>(XH, ro, xa0, xa1);
      consume_chunks<2>(xa0, xa1, ldsW, 0, lq, lrow, acc);
      epi_gates(acc, w, B0P, c2, hTile, SLOTP(H0, 1) + w * 1024, tid);
      __syncthreads();  // drain sc1 h-stores before flagging
      if ((tid & 63) == 0) flag_add(FREC(0, 0, rg) + g);
    }
    for (int s = 1; s < 256; ++s) {
      ZACC2;
      stream_l0p(XH + (long)s * 32768, SLOTP(H0, s), ldsW, FREC(s - 1, 0, rg),
                 ro, lq, lrow, acc);
      epi_gates(acc, w, B0P, c2, hTile, SLOTP(H0, s + 1) + w * 1024, tid);
      __syncthreads();
      if ((tid & 63) == 0) flag_add(FREC(s, 0, rg) + g);
    }
    __syncthreads();
    loadW(SD + (long)w * 65536, ldsW, 65536, tid);  // swap in Weff|Whh0
    __syncthreads();
    for (int i = 0; i < 59; ++i) {
      ZACC2;
      const int* fF = FREC(256 + i, 1, rg);  // fresh H1[256+i]
      const int* fO = FREC(255 + i, 0, rg);  // old own H0[256+i]
      unsigned gotO = peek8(fO);             // old discovery overlaps fresh
      // ascending kk (r7 order): fresh H1 -> Weff (kk 0..31) FIRST
      stream8g(SLOTP(H1, 256 + i), ldsW, 0, fF, 0u, ro, lq, lrow, acc);
      // then old H0 -> Whh0 (kk 32..63)
      stream8g(SLOTP(H0, 256 + i), ldsW, 32, fO, gotO, ro, lq, lrow, acc);
      epi_gates(acc, w, BD0P, c2, hTile, SLOTP(H0, 257 + i) + w * 1024, tid);
      __syncthreads();
      if ((tid & 63) == 0) flag_add(FREC(256 + i, 0, rg) + g);
    }
  } else {  // ============ L1 prefix + decode cell1 ============
    const int bw = w - 128, g = bw >> 4;
    loadW(S1 + (long)bw * 65536, ldsW, 65536, tid);
    __syncthreads();
    for (int s = 1; s <= 256; ++s) {
      ZACC2;
      const int* fF = FREC(s - 1, 0, rg);  // fresh H0[s]
      const int* fO = FREC(s - 1, 1, rg);  // old H1[s-1]
      unsigned gotO = (s >= 2) ? peek8(fO) : 0u;
      // ascending kk: fresh H0[s] -> Wih1 (kk 0..31) FIRST
      stream8g(SLOTP(H0, s), ldsW, 0, fF, 0u, ro, lq, lrow, acc);
      // then old H1[s-1] -> Whh1 (kk 32..63); s == 1: H1[0] == 0 -> skip
      if (s >= 2)
        stream8g(SLOTP(H1, s - 1), ldsW, 32, fO, gotO, ro, lq, lrow, acc);
      epi_gates(acc, bw, B1P, c2, hTile, SLOTP(H1, s) + bw * 1024, tid);
      __syncthreads();
      if ((tid & 63) == 0) flag_add(FREC(s, 1, rg) + g);
    }
    for (int i = 0; i < 59; ++i) {
      ZACC2;
      const int* fF = FREC(256 + i, 0, rg);  // fresh H0[257+i]
      const int* fO = FREC(256 + i, 1, rg);  // old own H1[256+i]
      unsigned gotO = peek8(fO);
      // ascending kk: fresh H0[257+i] -> Wih1 (kk 0..31) FIRST
      stream8g(SLOTP(H0, 257 + i), ldsW, 0, fF, 0u, ro, lq, lrow, acc);
      // then old H1[256+i] -> Whh1 (kk 32..63)
      stream8g(SLOTP(H1, 256 + i), ldsW, 32, fO, gotO, ro, lq, lrow, acc);
      epi_gates(acc, bw, B1P, c2, hTile, SLOTP(H1, 257 + i) + bw * 1024, tid);
      __syncthreads();
      if ((tid & 63) == 0) flag_add(FREC(257 + i, 1, rg) + g);
    }
  }

  // ---- post-loop: y[i] = H1[256+i] @ Wlin^T + b, i = 0..59, 8 col-tiles ----
  // 480 tile-jobs over 256 blocks; off the recurrence chain entirely.
  for (int j = w; j < 480; j += 256) {
    const int i = j >> 3, t = j & 7;
    ZACC2;
    const int* f = FREC(256 + i, 1, rg);
    stream8g(SLOTP(H1, 256 + i), SY + (long)t * 32768, 0, f, peek8(f),
             ro, lq, lrow, acc);
    epi_y(acc, t, i, BD0P + 4096, out, tid);
  }
#undef FREC
#undef SLOTP
}

// ======================= setup kernels (round-5 verbatim) ===================

__global__ void k_cvt_x(const float* __restrict__ x, half_t* __restrict__ XH) {
  int idx = blockIdx.x * 256 + threadIdx.x;  // 1,048,576 total
  int t = idx >> 12;
  int kb = (idx >> 7) & 31;
  int r = idx & 127;
  const float* src = x + ((long)((r << 8) + t)) * 256 + kb * 8;
  float4 v0 = *(const float4*)src;
  float4 v1 = *(const float4*)(src + 4);
  half_t tmp[8] = {(half_t)v0.x, (half_t)v0.y, (half_t)v0.z, (half_t)v0.w,
                   (half_t)v1.x, (half_t)v1.y, (half_t)v1.z, (half_t)v1.w};
  *(uint4*)(XH + (long)t * 32768 + kb * 1024 + r * 8) = *(const uint4*)tmp;
}

__global__ void k_pack32(const float* __restrict__ A, int KA,
                         const float* __restrict__ Bsrc,
                         half_t* __restrict__ dst, int KT32, int skipA) {
  int idx = blockIdx.x * 256 + threadIdx.x;
  int nn = idx & 31;
  int lq = (idx >> 5) & 3;
  int t2 = idx >> 7;
  int kk = t2 % KT32;
  int tile = t2 / KT32;
  if (tile >= 128) return;
  int k = kk * 32 + lq * 8;
  int rp = tile * 32 + nn;
  int r = ((rp & 3) << 10) + (rp >> 2);
  const float* src;
  if (k < KA) {
    if (skipA) return;
    src = A + (long)r * KA + k;
  } else {
    src = Bsrc + (long)r * 1024 + (k - KA);
  }
  float4 v0 = *(const float4*)src;
  float4 v1 = *(const float4*)(src + 4);
  half_t tmp[8] = {(half_t)v0.x, (half_t)v0.y, (half_t)v0.z, (half_t)v0.w,
                   (half_t)v1.x, (half_t)v1.y, (half_t)v1.z, (half_t)v1.w};
  *(uint4*)(dst + (long)tile * (KT32 * 1024) + kk * 1024 + lq * 256 + nn * 8) =
      *(const uint4*)tmp;
}

__global__ void k_pack_y32(const float* __restrict__ Wlin,
                           half_t* __restrict__ SY) {
  int idx = blockIdx.x * 256 + threadIdx.x;  // 32768 total
  int nn = idx & 31;
  int lq = (idx >> 5) & 3;
  int kk = (idx >> 7) & 31;
  int tile = idx >> 12;
  int d = tile * 32 + nn;
  int k = kk * 32 + lq * 8;
  const float* src = Wlin + (long)d * 1024 + k;
  float4 v0 = *(const float4*)src;
  float4 v1 = *(const float4*)(src + 4);
  half_t tmp[8] = {(half_t)v0.x, (half_t)v0.y, (half_t)v0.z, (half_t)v0.w,
                   (half_t)v1.x, (half_t)v1.y, (half_t)v1.z, (half_t)v1.w};
  *(uint4*)(SY + (long)tile * 32768 + kk * 1024 + lq * 256 + nn * 8) =
      *(const uint4*)tmp;
}

__global__ void k_bias_simple(const float* bi0, const float* bh0,
                              const float* bi1, const float* bh1,
                              const float* blin, float* b0p, float* b1p,
                              float* bD0p) {
  int rp = blockIdx.x * blockDim.x + threadIdx.x;
  if (rp < 4096) {
    int r = ((rp & 3) << 10) + (rp >> 2);
    b0p[rp] = bi0[r] + bh0[r];
    b1p[rp] = bi1[r] + bh1[r];
  } else if (rp < 4352) {
    bD0p[rp] = blin[rp - 4096];
  }
}

__global__ void k_bias_dot(const float* __restrict__ Wih0,
                           const float* __restrict__ blin,
                           const float* __restrict__ bi0,
                           const float* __restrict__ bh0,
                           float* __restrict__ bD0p) {
  int wv = threadIdx.x >> 6, l = threadIdx.x & 63;
  int r = blockIdx.x * 4 + wv;
  float s = 0.f;
#pragma unroll
  for (int c = 0; c < 4; ++c) s += Wih0[r * 256 + c * 64 + l] * blin[c * 64 + l];
#pragma unroll
  for (int o = 32; o >= 1; o >>= 1) s += __shfl_xor(s, o);
  if (l == 0) {
    int rp = ((r & 1023) << 2) | (r >> 10);
    bD0p[rp] = bi0[r] + bh0[r] + s;
  }
}

__global__ void k_weff(const float* __restrict__ Wih0,
                       const float* __restrict__ Wlin,
                       half_t* __restrict__ SD) {
  __shared__ float At[64][65];
  __shared__ float Bt[64][65];
  const int rt = blockIdx.x, jt = blockIdx.y;
  const int tid = threadIdx.x;
  const int tx = tid & 15, ty = tid >> 4;
  float acc[4][4] = {};
  for (int k0 = 0; k0 < 256; k0 += 64) {
    __syncthreads();
#pragma unroll
    for (int i = 0; i < 16; ++i) {
      int lin = tid + 256 * i;
      int rr = lin >> 6, kk = lin & 63;
      At[rr][kk] = Wih0[(rt * 64 + rr) * 256 + k0 + kk];
      Bt[rr][kk] = Wlin[(k0 + rr) * 1024 + jt * 64 + kk];
    }
    __syncthreads();
    for (int kk = 0; kk < 64; ++kk) {
      float a[4], b[4];
#pragma unroll
      for (int i = 0; i < 4; ++i) a[i] = At[ty * 4 + i][kk];
#pragma unroll
      for (int i = 0; i < 4; ++i) b[i] = Bt[kk][tx * 4 + i];
#pragma unroll
      for (int i = 0; i < 4; ++i)
#pragma unroll
        for (int jx = 0; jx < 4; ++jx) acc[i][jx] += a[i] * b[jx];
    }
  }
#pragma unroll
  for (int i = 0; i < 4; ++i) {
    int r = rt * 64 + ty * 4 + i;
    int rp = ((r & 1023) << 2) | (r >> 10);
    int tile = rp >> 5, nn = rp & 31;
#pragma unroll
    for (int jx = 0; jx < 4; ++jx) {
      int j = jt * 64 + tx * 4 + jx;
      SD[(long)tile * 65536 + (j >> 5) * 1024 + ((j >> 3) & 3) * 256 + nn * 8 +
         (j & 7)] = (half_t)acc[i][jx];
    }
  }
}

// ======================= launch =======================

extern "C" void kernel_launch(void* const* d_in, const int* in_sizes, int n_in,
                              void* d_out, int out_size, void* d_ws, size_t ws_size,
                              hipStream_t stream) {
  (void)in_sizes; (void)n_in; (void)out_size; (void)ws_size;
  const float* x    = (const float*)d_in[0];
  const float* Wih0 = (const float*)d_in[1];
  const float* Whh0 = (const float*)d_in[2];
  const float* bi0  = (const float*)d_in[3];
  const float* bh0  = (const float*)d_in[4];
  const float* Wih1 = (const float*)d_in[5];
  const float* Whh1 = (const float*)d_in[6];
  const float* bi1  = (const float*)d_in[7];
  const float* bh1  = (const float*)d_in[8];
  const float* Wlin = (const float*)d_in[9];
  const float* blin = (const float*)d_in[10];
  float* out = (float*)d_out;
  char* ws = (char*)d_ws;

  half_t* S0  = (half_t*)(ws + 0);         // 128 x 40960 x 2 = 10 MB
  half_t* S1  = (half_t*)(ws + 10485760);  // 128 x 65536 x 2 = 16 MB
  half_t* SD  = (half_t*)(ws + 27262976);  // 16 MB
  half_t* SY  = (half_t*)(ws + 44040192);  // 512 KB
  half_t* XH  = (half_t*)(ws + 44564480);  // 16 MB
  float*  B0P = (float*)(ws + 61341696);   // 16 KB
  float*  B1P = (float*)(ws + 61358080);   // 16 KB
  float*  BD0P= (float*)(ws + 61374464);   // 17408 B
  half_t* H0  = (half_t*)(ws + 61432320);  // ring: 320 x 256 KB = 80 MB
  half_t* H1  = (half_t*)(ws + 145318400); // ring: 320 x 256 KB = 80 MB
  // flag counters (x4 wave replicas) in the spare tail slots of the H1 ring
  // (slots 316..319 never written by the recurrence): 2560 lines x 128 B
  int*    FLGB= (int*)(ws + 145318400 + (long)316 * 262144);  // 228,155,904

  hipMemsetAsync(FLGB, 0, 327680, stream);     // all flag records
  hipMemsetAsync(H0, 0, 262144, stream);       // H0 slot 0 (safety; unused)
  hipMemsetAsync(H1, 0, 262144, stream);       // H1 slot 0 (safety; unused)

  k_cvt_x<<<4096, 256, 0, stream>>>(x, XH);
  k_bias_simple<<<17, 256, 0, stream>>>(bi0, bh0, bi1, bh1, blin, B0P, B1P, BD0P);
  k_bias_dot<<<1024, 256, 0, stream>>>(Wih0, blin, bi0, bh0, BD0P);
  k_pack32<<<2560, 256, 0, stream>>>(Wih0, 256, Whh0, S0, 40, 0);
  k_pack32<<<4096, 256, 0, stream>>>(Wih1, 1024, Whh1, S1, 64, 0);
  k_pack32<<<4096, 256, 0, stream>>>(nullptr, 1024, Whh0, SD, 64, 1);
  k_pack_y32<<<128, 256, 0, stream>>>(Wlin, SY);
  k_weff<<<dim3(64, 16), 256, 0, stream>>>(Wih0, Wlin, SD);

  k_lstm<<<256, 256, 0, stream>>>(S0, S1, SD, SY, XH, H0, H1,
                                  B0P, B1P, BD0P, out, FLGB);
}